// Round 3
// baseline (527.881 us; speedup 1.0000x reference)
//
#include <hip/hip_runtime.h>

#define NNODES 16384
#define NEDGES 524288
#define NETOT  (NEDGES + NNODES)   // 540672 (self-loops appended)
#define NGRAPH 256

typedef __attribute__((ext_vector_type(8))) short short8;
typedef __attribute__((ext_vector_type(4))) float f32x4;

__device__ __forceinline__ float b2f(unsigned short u){
  union { unsigned int i; float f; } v; v.i = ((unsigned int)u) << 16; return v.f;
}
__device__ __forceinline__ unsigned short f2b(float f){
  union { float f; unsigned int i; } v; v.f = f;
  unsigned int r = v.i + 0x7FFFu + ((v.i >> 16) & 1u);
  return (unsigned short)(r >> 16);
}

// ---------------- CSR build (dst-sorted) ----------------
__global__ void __launch_bounds__(256) zero_deg(int* __restrict__ deg){
  deg[blockIdx.x * 256 + threadIdx.x] = 0;   // grid = NNODES/256
}

__global__ void __launch_bounds__(256) count_deg(const int* __restrict__ ei, int* __restrict__ deg){
  int i = blockIdx.x * 256 + threadIdx.x;    // grid exactly NETOT/256
  int d = (i < NEDGES) ? ei[NEDGES + i] : (i - NEDGES);
  atomicAdd(&deg[d], 1);
}

// single block; row_off[0..N] and cursor[i] = row start
__global__ void __launch_bounds__(1024) scan_deg(const int* __restrict__ deg,
                                                 int* __restrict__ row_off,
                                                 int* __restrict__ cursor){
  __shared__ int wsum[16];
  __shared__ int woff[16];
  __shared__ int carry_s;
  const int tid = threadIdx.x, lane = tid & 63, w = tid >> 6;
  if(tid == 0){ carry_s = 0; row_off[0] = 0; }
  __syncthreads();
  for(int base = 0; base < NNODES; base += 1024){
    int v = deg[base + tid];
    int x = v;
    #pragma unroll
    for(int o = 1; o < 64; o <<= 1){ int u = __shfl_up(x, o, 64); if(lane >= o) x += u; }
    if(lane == 63) wsum[w] = x;
    __syncthreads();
    if(w == 0){
      int t0 = (lane < 16) ? wsum[lane] : 0;
      int y = t0;
      #pragma unroll
      for(int o = 1; o < 16; o <<= 1){ int u = __shfl_up(y, o, 64); if(lane >= o) y += u; }
      if(lane < 16) woff[lane] = y - t0;   // exclusive among waves
    }
    __syncthreads();
    int carry = carry_s;
    int incl = carry + woff[w] + x;
    row_off[base + tid + 1] = incl;
    cursor[base + tid] = incl - v;
    __syncthreads();
    if(tid == 1023) carry_s = incl;
    __syncthreads();
  }
}

__global__ void __launch_bounds__(256) fill_csr(const int* __restrict__ ei, int* __restrict__ cursor,
                                                int* __restrict__ col_src){
  int i = blockIdx.x * 256 + threadIdx.x;  // grid exactly NETOT/256
  int s, d;
  if(i < NEDGES){ s = ei[i]; d = ei[NEDGES + i]; }
  else          { s = i - NEDGES; d = s; }
  int p = atomicAdd(&cursor[d], 1);
  col_src[p] = s;
}

// ---------------- fp32 -> bf16 hi/lo split planes ----------------
// A' (N x 3K) = [hi | hi | lo];  W' (3K x 512) = [Whi ; Wlo ; Whi]
// => bf16 GEMM over K'=3K computes hi*Whi + hi*Wlo + lo*Whi  (~fp32 accurate)
template<int LOGK>
__global__ void __launch_bounds__(256) convA(const float* __restrict__ A, unsigned short* __restrict__ Ab){
  const int K = 1 << LOGK;
  int i = blockIdx.x * 256 + threadIdx.x;        // grid = N*K/256
  int n = i >> LOGK, k = i & (K - 1);
  float val = A[i];
  unsigned short hi = f2b(val);
  unsigned short lo = f2b(val - b2f(hi));
  unsigned short* row = Ab + (size_t)n * (3 * K);
  row[k] = hi; row[K + k] = hi; row[2 * K + k] = lo;
}

template<int K>
__global__ void __launch_bounds__(256) convW(const float* __restrict__ Wl, const float* __restrict__ Wr,
                                             unsigned short* __restrict__ Wb){
  int i = blockIdx.x * 256 + threadIdx.x;        // grid = K*512/256
  int k = i >> 9, cc = i & 511;
  float val = (cc < 256) ? Wl[(size_t)k * 256 + cc] : Wr[(size_t)k * 256 + (cc - 256)];
  unsigned short hi = f2b(val);
  unsigned short lo = f2b(val - b2f(hi));
  Wb[(size_t)k * 512 + cc]           = hi;
  Wb[(size_t)(K + k) * 512 + cc]     = lo;
  Wb[(size_t)(2 * K + k) * 512 + cc] = hi;
}

// ---------------- GEMM: C[N][512](fp32) = A'[N][K] @ W'[K][512], bf16 MFMA ----------------
// MFMA 16x16x32_bf16; A frag row=lane&15, k=(lane>>4)*8+j; B frag col=lane&15 same k map;
// C/D: col=lane&15, row=(lane>>4)*4+reg  [guide m89-verified]
template<int K>
__global__ void __launch_bounds__(256) gemm_xw(const unsigned short* __restrict__ A,
                                               const unsigned short* __restrict__ W,
                                               float* __restrict__ Cout){
  __shared__ unsigned short As[128][40];  // BK=32, padded row stride 80 B
  __shared__ unsigned short Bs[64][40];   // transposed: Bs[col][k]
  const int t = threadIdx.x;
  const int rowbase = blockIdx.x * 128;
  const int colbase = blockIdx.y * 64;
  const int wave = t >> 6, lane = t & 63;
  const int lrow = lane & 15, kg = lane >> 4;

  f32x4 acc[2][4] = {};

  for(int kt = 0; kt < K; kt += 32){
    { // stage A: 128 rows x 32 k, 16B x2 per thread
      int oct = t & 3, r = t >> 2;
      const unsigned short* ga = A + (size_t)(rowbase + r) * K + kt + oct * 8;
      short8 v0 = *(const short8*)ga;
      short8 v1 = *(const short8*)(ga + 64 * K);
      *(short8*)(&As[r][oct * 8])      = v0;
      *(short8*)(&As[r + 64][oct * 8]) = v1;
    }
    { // stage B transposed: Bs[n][k] = W[kt+k][colbase+n]
      int n = t & 63, oct = t >> 6;
      short8 v;
      #pragma unroll
      for(int j = 0; j < 8; j++) v[j] = (short)W[(size_t)(kt + oct * 8 + j) * 512 + colbase + n];
      *(short8*)(&Bs[n][oct * 8]) = v;
    }
    __syncthreads();
    short8 afrag[2], bfrag[4];
    afrag[0] = *(const short8*)(&As[wave * 32 + lrow][kg * 8]);
    afrag[1] = *(const short8*)(&As[wave * 32 + 16 + lrow][kg * 8]);
    #pragma unroll
    for(int fc = 0; fc < 4; fc++) bfrag[fc] = *(const short8*)(&Bs[fc * 16 + lrow][kg * 8]);
    #pragma unroll
    for(int rf = 0; rf < 2; rf++)
      #pragma unroll
      for(int fc = 0; fc < 4; fc++)
        acc[rf][fc] = __builtin_amdgcn_mfma_f32_16x16x32_bf16(afrag[rf], bfrag[fc], acc[rf][fc], 0, 0, 0);
    __syncthreads();
  }
  #pragma unroll
  for(int rf = 0; rf < 2; rf++)
    #pragma unroll
    for(int fc = 0; fc < 4; fc++)
      #pragma unroll
      for(int r = 0; r < 4; r++){
        int row = rowbase + wave * 32 + rf * 16 + kg * 4 + r;
        int col = colbase + fc * 16 + lrow;
        Cout[(size_t)row * 512 + col] = acc[rf][fc][r];
      }
}

// ---------------- per-dst-node online-softmax aggregation (fp32) ----------------
// one wave per dst node; lane owns 4 channels (lanes 0-31 head0, 32-63 head1)
__global__ void __launch_bounds__(256) edge_agg(const float* __restrict__ xlr,
                                                const int* __restrict__ row_off,
                                                const int* __restrict__ col_src,
                                                const float* __restrict__ att,
                                                const float* __restrict__ bias,
                                                float* __restrict__ hout){
  const int n = (blockIdx.x * 256 + threadIdx.x) >> 6;
  const int lane = threadIdx.x & 63;
  const int c0 = lane * 4;
  f32x4 xr4 = *(const f32x4*)(xlr + (size_t)n * 512 + 256 + c0);   // Wr x_dst
  f32x4 at4 = *(const f32x4*)(att + c0);
  float m = -1e30f, s = 0.f, ac0 = 0.f, ac1 = 0.f, ac2 = 0.f, ac3 = 0.f;
  const int beg = row_off[n], end = row_off[n + 1];
  for(int ch = beg; ch < end; ch += 64){
    int idx = ch + lane;
    int si = (idx < end) ? col_src[idx] : 0;
    int cnt = end - ch; if(cnt > 64) cnt = 64;
    for(int k = 0; k < cnt; k++){
      int src = __shfl(si, k);
      f32x4 x4 = *(const f32x4*)(xlr + (size_t)src * 512 + c0);    // Wl x_src
      float e, p;
      e = x4[0] + xr4[0]; e = (e > 0.f) ? e : 0.2f * e; p = at4[0] * e;
      e = x4[1] + xr4[1]; e = (e > 0.f) ? e : 0.2f * e; p = fmaf(at4[1], e, p);
      e = x4[2] + xr4[2]; e = (e > 0.f) ? e : 0.2f * e; p = fmaf(at4[2], e, p);
      e = x4[3] + xr4[3]; e = (e > 0.f) ? e : 0.2f * e; p = fmaf(at4[3], e, p);
      #pragma unroll
      for(int o = 16; o > 0; o >>= 1) p += __shfl_xor(p, o, 32);   // per-head (32-lane) reduce
      float nm = fmaxf(m, p);
      float sc = __expf(m - nm);
      float pe = __expf(p - nm);
      s = s * sc + pe;
      ac0 = ac0 * sc + pe * x4[0];
      ac1 = ac1 * sc + pe * x4[1];
      ac2 = ac2 * sc + pe * x4[2];
      ac3 = ac3 * sc + pe * x4[3];
      m = nm;
    }
  }
  float inv = 1.f / s;
  f32x4 o4;
  o4[0] = ac0 * inv + bias[c0 + 0];
  o4[1] = ac1 * inv + bias[c0 + 1];
  o4[2] = ac2 * inv + bias[c0 + 2];
  o4[3] = ac3 * inv + bias[c0 + 3];
  *(f32x4*)(hout + (size_t)n * 256 + c0) = o4;
}

// ---------------- pooling (per layer) + FFN ----------------
__device__ __forceinline__ int lbound(const int* __restrict__ a, int n, int v){
  int lo = 0, hi = n;
  while(lo < hi){ int mid = (lo + hi) >> 1; if(a[mid] < v) lo = mid + 1; else hi = mid; }
  return lo;
}

__global__ void __launch_bounds__(256) pool_accum(const float* __restrict__ h,
                                                  const int* __restrict__ batch,
                                                  float* __restrict__ pool, int slot){
  const int g = blockIdx.x, t = threadIdx.x;
  const int lo = lbound(batch, NNODES, g);
  const int hi = lbound(batch, NNODES, g + 1);
  float s = 0.f;
  for(int node = lo; node < hi; node++) s += h[(size_t)node * 256 + t];
  pool[(size_t)g * 768 + slot * 256 + t] = s;
}

__global__ void __launch_bounds__(256) ffn1(const float* __restrict__ pool,
                                            const float* __restrict__ fW1,
                                            const float* __restrict__ fb1,
                                            float* __restrict__ hidden){
  __shared__ float a[4][768];
  const int gb = blockIdx.x, cb = blockIdx.y, t = threadIdx.x;
  for(int i = t; i < 3072; i += 256) ((float*)a)[i] = pool[(size_t)gb * 3072 + i];
  __syncthreads();
  const int col = cb * 256 + t;
  float c0 = 0.f, c1 = 0.f, c2 = 0.f, c3 = 0.f;
  for(int k = 0; k < 768; k++){
    float w = fW1[(size_t)k * 768 + col];
    c0 = fmaf(a[0][k], w, c0);
    c1 = fmaf(a[1][k], w, c1);
    c2 = fmaf(a[2][k], w, c2);
    c3 = fmaf(a[3][k], w, c3);
  }
  float b = fb1[col];
  hidden[(size_t)(gb * 4 + 0) * 768 + col] = fmaxf(c0 + b, 0.f);
  hidden[(size_t)(gb * 4 + 1) * 768 + col] = fmaxf(c1 + b, 0.f);
  hidden[(size_t)(gb * 4 + 2) * 768 + col] = fmaxf(c2 + b, 0.f);
  hidden[(size_t)(gb * 4 + 3) * 768 + col] = fmaxf(c3 + b, 0.f);
}

__global__ void __launch_bounds__(256) ffn2(const float* __restrict__ hidden,
                                            const float* __restrict__ fW2,
                                            const float* __restrict__ fb2,
                                            float* __restrict__ out){
  const int g = (blockIdx.x * 256 + threadIdx.x) >> 6;   // one wave per graph, grid 64 blocks
  const int lane = threadIdx.x & 63;
  float p = 0.f;
  for(int i = lane; i < 768; i += 64) p += hidden[(size_t)g * 768 + i] * fW2[i];
  #pragma unroll
  for(int o = 32; o > 0; o >>= 1) p += __shfl_xor(p, o, 64);
  if(lane == 0) out[g] = p + fb2[0];
}

extern "C" void kernel_launch(void* const* d_in, const int* in_sizes, int n_in,
                              void* d_out, int out_size, void* d_ws, size_t ws_size,
                              hipStream_t stream){
  const float* x    = (const float*)d_in[0];
  const int* ei     = (const int*)d_in[1];
  const int* batch  = (const int*)d_in[2];
  const float* Wl[3]  = {(const float*)d_in[3],  (const float*)d_in[7],  (const float*)d_in[11]};
  const float* Wr[3]  = {(const float*)d_in[4],  (const float*)d_in[8],  (const float*)d_in[12]};
  const float* att[3] = {(const float*)d_in[5],  (const float*)d_in[9],  (const float*)d_in[13]};
  const float* bp[3]  = {(const float*)d_in[6],  (const float*)d_in[10], (const float*)d_in[14]};
  const float* fW1 = (const float*)d_in[15];
  const float* fb1 = (const float*)d_in[16];
  const float* fW2 = (const float*)d_in[17];
  const float* fb2 = (const float*)d_in[18];

  char* ws = (char*)d_ws;
  size_t off = 0;
  auto alloc = [&](size_t sz){ size_t p = off; off += (sz + 255) & ~(size_t)255; return p; };
  int* deg      = (int*)(ws + alloc((size_t)NNODES * 4));
  int* rowoff   = (int*)(ws + alloc((size_t)(NNODES + 1) * 4));
  int* cursor   = (int*)(ws + alloc((size_t)NNODES * 4));
  int* colsrc   = (int*)(ws + alloc((size_t)NETOT * 4));
  unsigned short* Abuf = (unsigned short*)(ws + alloc((size_t)NNODES * 768 * 2)); // up to 3K=768
  unsigned short* Wbuf = (unsigned short*)(ws + alloc((size_t)768 * 512 * 2));
  float* xlr  = (float*)(ws + alloc((size_t)NNODES * 512 * 4));
  float* hA   = (float*)(ws + alloc((size_t)NNODES * 256 * 4));
  float* hB   = (float*)(ws + alloc((size_t)NNODES * 256 * 4));
  float* pool   = (float*)(ws + alloc((size_t)NGRAPH * 768 * 4));
  float* hidden = (float*)(ws + alloc((size_t)NGRAPH * 768 * 4));

  // CSR build
  zero_deg<<<NNODES / 256, 256, 0, stream>>>(deg);
  count_deg<<<NETOT / 256, 256, 0, stream>>>(ei, deg);
  scan_deg<<<1, 1024, 0, stream>>>(deg, rowoff, cursor);
  fill_csr<<<NETOT / 256, 256, 0, stream>>>(ei, cursor, colsrc);

  dim3 ggrid(NNODES / 128, 8);

  // layer 1 (K=128 -> K'=384)
  convA<7><<<NNODES * 128 / 256, 256, 0, stream>>>(x, Abuf);
  convW<128><<<128 * 512 / 256, 256, 0, stream>>>(Wl[0], Wr[0], Wbuf);
  gemm_xw<384><<<ggrid, 256, 0, stream>>>(Abuf, Wbuf, xlr);
  edge_agg<<<NNODES / 4, 256, 0, stream>>>(xlr, rowoff, colsrc, att[0], bp[0], hA);
  pool_accum<<<NGRAPH, 256, 0, stream>>>(hA, batch, pool, 0);

  // layer 2 (K=256 -> K'=768)
  convA<8><<<NNODES * 256 / 256, 256, 0, stream>>>(hA, Abuf);
  convW<256><<<256 * 512 / 256, 256, 0, stream>>>(Wl[1], Wr[1], Wbuf);
  gemm_xw<768><<<ggrid, 256, 0, stream>>>(Abuf, Wbuf, xlr);
  edge_agg<<<NNODES / 4, 256, 0, stream>>>(xlr, rowoff, colsrc, att[1], bp[1], hB);
  pool_accum<<<NGRAPH, 256, 0, stream>>>(hB, batch, pool, 1);

  // layer 3 (K=256 -> K'=768)
  convA<8><<<NNODES * 256 / 256, 256, 0, stream>>>(hB, Abuf);
  convW<256><<<256 * 512 / 256, 256, 0, stream>>>(Wl[2], Wr[2], Wbuf);
  gemm_xw<768><<<ggrid, 256, 0, stream>>>(Abuf, Wbuf, xlr);
  edge_agg<<<NNODES / 4, 256, 0, stream>>>(xlr, rowoff, colsrc, att[2], bp[2], hA);
  pool_accum<<<NGRAPH, 256, 0, stream>>>(hA, batch, pool, 2);

  // FFN head
  ffn1<<<dim3(NGRAPH / 4, 3), 256, 0, stream>>>(pool, fW1, fb1, hidden);
  ffn2<<<NGRAPH / 4, 256, 0, stream>>>(hidden, fW2, fb2, (float*)d_out);
}

// Round 4
// 410.104 us; speedup vs baseline: 1.2872x; 1.2872x over previous
//
#include <hip/hip_runtime.h>

#define NNODES 16384
#define NEDGES 524288
#define NETOT  (NEDGES + NNODES)   // 540672 (self-loops appended)
#define NGRAPH 256

typedef __attribute__((ext_vector_type(8))) short short8;
typedef __attribute__((ext_vector_type(4))) float f32x4;

__device__ __forceinline__ float b2f(unsigned short u){
  union { unsigned int i; float f; } v; v.i = ((unsigned int)u) << 16; return v.f;
}
__device__ __forceinline__ unsigned short f2b(float f){
  union { float f; unsigned int i; } v; v.f = f;
  unsigned int r = v.i + 0x7FFFu + ((v.i >> 16) & 1u);
  return (unsigned short)(r >> 16);
}

// ---------------- CSR build (dst-sorted) ----------------
__global__ void __launch_bounds__(256) zero_deg(int* __restrict__ deg){
  deg[blockIdx.x * 256 + threadIdx.x] = 0;   // grid = NNODES/256
}

__global__ void __launch_bounds__(256) count_deg(const int* __restrict__ ei, int* __restrict__ deg){
  int i = blockIdx.x * 256 + threadIdx.x;    // grid exactly NETOT/256
  int d = (i < NEDGES) ? ei[NEDGES + i] : (i - NEDGES);
  atomicAdd(&deg[d], 1);
}

// single block; row_off[0..N] and cursor[i] = row start
__global__ void __launch_bounds__(1024) scan_deg(const int* __restrict__ deg,
                                                 int* __restrict__ row_off,
                                                 int* __restrict__ cursor){
  __shared__ int wsum[16];
  __shared__ int woff[16];
  __shared__ int carry_s;
  const int tid = threadIdx.x, lane = tid & 63, w = tid >> 6;
  if(tid == 0){ carry_s = 0; row_off[0] = 0; }
  __syncthreads();
  for(int base = 0; base < NNODES; base += 1024){
    int v = deg[base + tid];
    int x = v;
    #pragma unroll
    for(int o = 1; o < 64; o <<= 1){ int u = __shfl_up(x, o, 64); if(lane >= o) x += u; }
    if(lane == 63) wsum[w] = x;
    __syncthreads();
    if(w == 0){
      int t0 = (lane < 16) ? wsum[lane] : 0;
      int y = t0;
      #pragma unroll
      for(int o = 1; o < 16; o <<= 1){ int u = __shfl_up(y, o, 64); if(lane >= o) y += u; }
      if(lane < 16) woff[lane] = y - t0;   // exclusive among waves
    }
    __syncthreads();
    int carry = carry_s;
    int incl = carry + woff[w] + x;
    row_off[base + tid + 1] = incl;
    cursor[base + tid] = incl - v;
    __syncthreads();
    if(tid == 1023) carry_s = incl;
    __syncthreads();
  }
}

__global__ void __launch_bounds__(256) fill_csr(const int* __restrict__ ei, int* __restrict__ cursor,
                                                int* __restrict__ col_src){
  int i = blockIdx.x * 256 + threadIdx.x;  // grid exactly NETOT/256
  int s, d;
  if(i < NEDGES){ s = ei[i]; d = ei[NEDGES + i]; }
  else          { s = i - NEDGES; d = s; }
  int p = atomicAdd(&cursor[d], 1);
  col_src[p] = s;
}

// ---------------- conversions ----------------
// layer-1 input: fp32 -> bf16, elementwise
__global__ void __launch_bounds__(256) convX(const float* __restrict__ x, unsigned short* __restrict__ xb){
  int i = blockIdx.x * 256 + threadIdx.x;
  xb[i] = f2b(x[i]);
}

// W (fp32 [K][256] x2) -> Wt bf16 [512][2K], transposed, hi plane at k, lo plane at K+k
template<int K>
__global__ void __launch_bounds__(256) convW(const float* __restrict__ Wl, const float* __restrict__ Wr,
                                             unsigned short* __restrict__ Wt){
  int i = blockIdx.x * 256 + threadIdx.x;        // grid = K*512/256
  int k = i >> 9, c = i & 511;
  float val = (c < 256) ? Wl[(size_t)k * 256 + c] : Wr[(size_t)k * 256 + (c - 256)];
  unsigned short hi = f2b(val);
  unsigned short lo = f2b(val - b2f(hi));
  Wt[(size_t)c * (2 * K) + k]     = hi;
  Wt[(size_t)c * (2 * K) + K + k] = lo;
}

// ---------------- GEMM: xlb[N][512](bf16) = A[N][K](bf16) @ W(fp32 via hi/lo planes) ----------------
// K' = 2K passes over A (ka = kt & (K-1)); Wt[c][kt] supplies hi then lo plane.
// MFMA 16x16x32_bf16; A frag row=lane&15, k=(lane>>4)*8+j; B frag col=lane&15 same k map;
// C/D: col=lane&15, row=(lane>>4)*4+reg
template<int K>
__global__ void __launch_bounds__(256) gemm_xw(const unsigned short* __restrict__ A,
                                               const unsigned short* __restrict__ Wt,
                                               unsigned short* __restrict__ Cout){
  __shared__ unsigned short As[128][40];  // BK=32, padded row stride 80 B
  __shared__ unsigned short Bs[64][40];
  const int t = threadIdx.x;
  const int rowbase = blockIdx.x * 128;
  const int colbase = blockIdx.y * 64;
  const int wave = t >> 6, lane = t & 63;
  const int lrow = lane & 15, kg = lane >> 4;

  f32x4 acc[2][4] = {};

  for(int kt = 0; kt < 2 * K; kt += 32){
    const int ka = kt & (K - 1);
    { // stage A: 128 rows x 32 k
      int oct = t & 3, r = t >> 2;
      const unsigned short* ga = A + (size_t)(rowbase + r) * K + ka + oct * 8;
      short8 v0 = *(const short8*)ga;
      short8 v1 = *(const short8*)(ga + 64 * K);
      *(short8*)(&As[r][oct * 8])      = v0;
      *(short8*)(&As[r + 64][oct * 8]) = v1;
    }
    { // stage B: Bs[n][kk] = Wt[colbase+n][kt+kk]  (vector load, Wt transposed)
      int n = t & 63, oct = t >> 6;
      short8 v = *(const short8*)(Wt + (size_t)(colbase + n) * (2 * K) + kt + oct * 8);
      *(short8*)(&Bs[n][oct * 8]) = v;
    }
    __syncthreads();
    short8 afrag[2], bfrag[4];
    afrag[0] = *(const short8*)(&As[wave * 32 + lrow][kg * 8]);
    afrag[1] = *(const short8*)(&As[wave * 32 + 16 + lrow][kg * 8]);
    #pragma unroll
    for(int fc = 0; fc < 4; fc++) bfrag[fc] = *(const short8*)(&Bs[fc * 16 + lrow][kg * 8]);
    #pragma unroll
    for(int rf = 0; rf < 2; rf++)
      #pragma unroll
      for(int fc = 0; fc < 4; fc++)
        acc[rf][fc] = __builtin_amdgcn_mfma_f32_16x16x32_bf16(afrag[rf], bfrag[fc], acc[rf][fc], 0, 0, 0);
    __syncthreads();
  }
  #pragma unroll
  for(int rf = 0; rf < 2; rf++)
    #pragma unroll
    for(int fc = 0; fc < 4; fc++)
      #pragma unroll
      for(int r = 0; r < 4; r++){
        int row = rowbase + wave * 32 + rf * 16 + kg * 4 + r;
        int col = colbase + fc * 16 + lrow;
        Cout[(size_t)row * 512 + col] = f2b(acc[rf][fc][r]);
      }
}

// ---------------- per-dst-node softmax aggregation (bf16 gather) ----------------
// one wave per dst node; lane owns 4 channels (lanes 0-31 head0, 32-63 head1).
// No max-subtraction: logits bounded (|p| << 80), alpha = exp(p)/sum identical to ref.
__global__ void __launch_bounds__(256) edge_agg(const unsigned short* __restrict__ xlb,
                                                const int* __restrict__ row_off,
                                                const int* __restrict__ col_src,
                                                const float* __restrict__ att,
                                                const float* __restrict__ bias,
                                                unsigned short* __restrict__ hout){
  const int n = (blockIdx.x * 256 + threadIdx.x) >> 6;
  const int lane = threadIdx.x & 63;
  const int c0 = lane * 4;
  ushort4 xr4 = *(const ushort4*)(xlb + (size_t)n * 512 + 256 + c0);   // Wr x_dst
  f32x4 at4 = *(const f32x4*)(att + c0);
  const float xr0 = b2f(xr4.x), xr1 = b2f(xr4.y), xr2 = b2f(xr4.z), xr3 = b2f(xr4.w);
  float s = 0.f, ac0 = 0.f, ac1 = 0.f, ac2 = 0.f, ac3 = 0.f;
  const int beg = row_off[n], end = row_off[n + 1];

  for(int ch = beg; ch < end; ch += 64){
    int idx = ch + lane;
    int si = (idx < end) ? col_src[idx] : 0;
    int cnt = end - ch; if(cnt > 64) cnt = 64;
    int k = 0;
    for(; k + 2 <= cnt; k += 2){
      int sa = __shfl(si, k), sb = __shfl(si, k + 1);
      ushort4 xa = *(const ushort4*)(xlb + (size_t)sa * 512 + c0);
      ushort4 xb = *(const ushort4*)(xlb + (size_t)sb * 512 + c0);
      float a0 = b2f(xa.x), a1 = b2f(xa.y), a2 = b2f(xa.z), a3 = b2f(xa.w);
      float b0 = b2f(xb.x), b1 = b2f(xb.y), b2 = b2f(xb.z), b3 = b2f(xb.w);
      float e, pa, pb;
      e = a0 + xr0; e = (e > 0.f) ? e : 0.2f * e; pa = at4[0] * e;
      e = b0 + xr0; e = (e > 0.f) ? e : 0.2f * e; pb = at4[0] * e;
      e = a1 + xr1; e = (e > 0.f) ? e : 0.2f * e; pa = fmaf(at4[1], e, pa);
      e = b1 + xr1; e = (e > 0.f) ? e : 0.2f * e; pb = fmaf(at4[1], e, pb);
      e = a2 + xr2; e = (e > 0.f) ? e : 0.2f * e; pa = fmaf(at4[2], e, pa);
      e = b2 + xr2; e = (e > 0.f) ? e : 0.2f * e; pb = fmaf(at4[2], e, pb);
      e = a3 + xr3; e = (e > 0.f) ? e : 0.2f * e; pa = fmaf(at4[3], e, pa);
      e = b3 + xr3; e = (e > 0.f) ? e : 0.2f * e; pb = fmaf(at4[3], e, pb);
      #pragma unroll
      for(int o = 16; o > 0; o >>= 1){ pa += __shfl_xor(pa, o, 32); pb += __shfl_xor(pb, o, 32); }
      float ea = __expf(pa), eb = __expf(pb);
      s += ea + eb;
      ac0 = fmaf(ea, a0, fmaf(eb, b0, ac0));
      ac1 = fmaf(ea, a1, fmaf(eb, b1, ac1));
      ac2 = fmaf(ea, a2, fmaf(eb, b2, ac2));
      ac3 = fmaf(ea, a3, fmaf(eb, b3, ac3));
    }
    for(; k < cnt; k++){
      int sa = __shfl(si, k);
      ushort4 xa = *(const ushort4*)(xlb + (size_t)sa * 512 + c0);
      float a0 = b2f(xa.x), a1 = b2f(xa.y), a2 = b2f(xa.z), a3 = b2f(xa.w);
      float e, pa;
      e = a0 + xr0; e = (e > 0.f) ? e : 0.2f * e; pa = at4[0] * e;
      e = a1 + xr1; e = (e > 0.f) ? e : 0.2f * e; pa = fmaf(at4[1], e, pa);
      e = a2 + xr2; e = (e > 0.f) ? e : 0.2f * e; pa = fmaf(at4[2], e, pa);
      e = a3 + xr3; e = (e > 0.f) ? e : 0.2f * e; pa = fmaf(at4[3], e, pa);
      #pragma unroll
      for(int o = 16; o > 0; o >>= 1) pa += __shfl_xor(pa, o, 32);
      float ea = __expf(pa);
      s += ea;
      ac0 = fmaf(ea, a0, ac0);
      ac1 = fmaf(ea, a1, ac1);
      ac2 = fmaf(ea, a2, ac2);
      ac3 = fmaf(ea, a3, ac3);
    }
  }
  float inv = 1.f / s;
  ushort4 o4;
  o4.x = f2b(fmaf(ac0, inv, bias[c0 + 0]));
  o4.y = f2b(fmaf(ac1, inv, bias[c0 + 1]));
  o4.z = f2b(fmaf(ac2, inv, bias[c0 + 2]));
  o4.w = f2b(fmaf(ac3, inv, bias[c0 + 3]));
  *(ushort4*)(hout + (size_t)n * 256 + c0) = o4;
}

// ---------------- pooling (per layer, bf16 in) + FFN ----------------
__device__ __forceinline__ int lbound(const int* __restrict__ a, int n, int v){
  int lo = 0, hi = n;
  while(lo < hi){ int mid = (lo + hi) >> 1; if(a[mid] < v) lo = mid + 1; else hi = mid; }
  return lo;
}

__global__ void __launch_bounds__(256) pool_accum(const unsigned short* __restrict__ h,
                                                  const int* __restrict__ batch,
                                                  float* __restrict__ pool, int slot){
  const int g = blockIdx.x, t = threadIdx.x;
  const int lo = lbound(batch, NNODES, g);
  const int hi = lbound(batch, NNODES, g + 1);
  float s = 0.f;
  for(int node = lo; node < hi; node++) s += b2f(h[(size_t)node * 256 + t]);
  pool[(size_t)g * 768 + slot * 256 + t] = s;
}

__global__ void __launch_bounds__(256) ffn1(const float* __restrict__ pool,
                                            const float* __restrict__ fW1,
                                            const float* __restrict__ fb1,
                                            float* __restrict__ hidden){
  __shared__ float a[4][768];
  const int gb = blockIdx.x, cb = blockIdx.y, t = threadIdx.x;
  for(int i = t; i < 3072; i += 256) ((float*)a)[i] = pool[(size_t)gb * 3072 + i];
  __syncthreads();
  const int col = cb * 256 + t;
  float c0 = 0.f, c1 = 0.f, c2 = 0.f, c3 = 0.f;
  for(int k = 0; k < 768; k++){
    float w = fW1[(size_t)k * 768 + col];
    c0 = fmaf(a[0][k], w, c0);
    c1 = fmaf(a[1][k], w, c1);
    c2 = fmaf(a[2][k], w, c2);
    c3 = fmaf(a[3][k], w, c3);
  }
  float b = fb1[col];
  hidden[(size_t)(gb * 4 + 0) * 768 + col] = fmaxf(c0 + b, 0.f);
  hidden[(size_t)(gb * 4 + 1) * 768 + col] = fmaxf(c1 + b, 0.f);
  hidden[(size_t)(gb * 4 + 2) * 768 + col] = fmaxf(c2 + b, 0.f);
  hidden[(size_t)(gb * 4 + 3) * 768 + col] = fmaxf(c3 + b, 0.f);
}

__global__ void __launch_bounds__(256) ffn2(const float* __restrict__ hidden,
                                            const float* __restrict__ fW2,
                                            const float* __restrict__ fb2,
                                            float* __restrict__ out){
  const int g = (blockIdx.x * 256 + threadIdx.x) >> 6;   // one wave per graph
  const int lane = threadIdx.x & 63;
  float p = 0.f;
  for(int i = lane; i < 768; i += 64) p += hidden[(size_t)g * 768 + i] * fW2[i];
  #pragma unroll
  for(int o = 32; o > 0; o >>= 1) p += __shfl_xor(p, o, 64);
  if(lane == 0) out[g] = p + fb2[0];
}

extern "C" void kernel_launch(void* const* d_in, const int* in_sizes, int n_in,
                              void* d_out, int out_size, void* d_ws, size_t ws_size,
                              hipStream_t stream){
  const float* x    = (const float*)d_in[0];
  const int* ei     = (const int*)d_in[1];
  const int* batch  = (const int*)d_in[2];
  const float* Wl[3]  = {(const float*)d_in[3],  (const float*)d_in[7],  (const float*)d_in[11]};
  const float* Wr[3]  = {(const float*)d_in[4],  (const float*)d_in[8],  (const float*)d_in[12]};
  const float* att[3] = {(const float*)d_in[5],  (const float*)d_in[9],  (const float*)d_in[13]};
  const float* bp[3]  = {(const float*)d_in[6],  (const float*)d_in[10], (const float*)d_in[14]};
  const float* fW1 = (const float*)d_in[15];
  const float* fb1 = (const float*)d_in[16];
  const float* fW2 = (const float*)d_in[17];
  const float* fb2 = (const float*)d_in[18];

  char* ws = (char*)d_ws;
  size_t off = 0;
  auto alloc = [&](size_t sz){ size_t p = off; off += (sz + 255) & ~(size_t)255; return p; };
  int* deg      = (int*)(ws + alloc((size_t)NNODES * 4));
  int* rowoff   = (int*)(ws + alloc((size_t)(NNODES + 1) * 4));
  int* cursor   = (int*)(ws + alloc((size_t)NNODES * 4));
  int* colsrc   = (int*)(ws + alloc((size_t)NETOT * 4));
  unsigned short* xb  = (unsigned short*)(ws + alloc((size_t)NNODES * 128 * 2)); // layer1 A
  unsigned short* Wt  = (unsigned short*)(ws + alloc((size_t)512 * 512 * 2));    // max 2K=512
  unsigned short* xlb = (unsigned short*)(ws + alloc((size_t)NNODES * 512 * 2)); // GEMM out (bf16)
  unsigned short* hA  = (unsigned short*)(ws + alloc((size_t)NNODES * 256 * 2));
  unsigned short* hB  = (unsigned short*)(ws + alloc((size_t)NNODES * 256 * 2));
  float* pool   = (float*)(ws + alloc((size_t)NGRAPH * 768 * 4));
  float* hidden = (float*)(ws + alloc((size_t)NGRAPH * 768 * 4));

  // CSR build
  zero_deg<<<NNODES / 256, 256, 0, stream>>>(deg);
  count_deg<<<NETOT / 256, 256, 0, stream>>>(ei, deg);
  scan_deg<<<1, 1024, 0, stream>>>(deg, rowoff, cursor);
  fill_csr<<<NETOT / 256, 256, 0, stream>>>(ei, cursor, colsrc);

  dim3 ggrid(NNODES / 128, 8);

  // layer 1 (K=128)
  convX<<<NNODES * 128 / 256, 256, 0, stream>>>(x, xb);
  convW<128><<<128 * 512 / 256, 256, 0, stream>>>(Wl[0], Wr[0], Wt);
  gemm_xw<128><<<ggrid, 256, 0, stream>>>(xb, Wt, xlb);
  edge_agg<<<NNODES / 4, 256, 0, stream>>>(xlb, rowoff, colsrc, att[0], bp[0], hA);
  pool_accum<<<NGRAPH, 256, 0, stream>>>(hA, batch, pool, 0);

  // layer 2 (K=256)
  convW<256><<<256 * 512 / 256, 256, 0, stream>>>(Wl[1], Wr[1], Wt);
  gemm_xw<256><<<ggrid, 256, 0, stream>>>(hA, Wt, xlb);
  edge_agg<<<NNODES / 4, 256, 0, stream>>>(xlb, rowoff, colsrc, att[1], bp[1], hB);
  pool_accum<<<NGRAPH, 256, 0, stream>>>(hB, batch, pool, 1);

  // layer 3 (K=256)
  convW<256><<<256 * 512 / 256, 256, 0, stream>>>(Wl[2], Wr[2], Wt);
  gemm_xw<256><<<ggrid, 256, 0, stream>>>(hB, Wt, xlb);
  edge_agg<<<NNODES / 4, 256, 0, stream>>>(xlb, rowoff, colsrc, att[2], bp[2], hA);
  pool_accum<<<NGRAPH, 256, 0, stream>>>(hA, batch, pool, 2);

  // FFN head
  ffn1<<<dim3(NGRAPH / 4, 3), 256, 0, stream>>>(pool, fW1, fb1, hidden);
  ffn2<<<NGRAPH / 4, 256, 0, stream>>>(hidden, fW2, fb2, (float*)d_out);
}

// Round 5
// 318.295 us; speedup vs baseline: 1.6585x; 1.2884x over previous
//
#include <hip/hip_runtime.h>

#define NNODES 16384
#define NEDGES 524288
#define NETOT  (NEDGES + NNODES)   // 540672 (self-loops appended)
#define NGRAPH 256

typedef __attribute__((ext_vector_type(8))) short short8;
typedef __attribute__((ext_vector_type(4))) float f32x4;

__device__ __forceinline__ float b2f(unsigned short u){
  union { unsigned int i; float f; } v; v.i = ((unsigned int)u) << 16; return v.f;
}
__device__ __forceinline__ unsigned short f2b(float f){
  union { float f; unsigned int i; } v; v.f = f;
  unsigned int r = v.i + 0x7FFFu + ((v.i >> 16) & 1u);
  return (unsigned short)(r >> 16);
}

// ---------------- CSR build (dst-sorted) ----------------
__global__ void __launch_bounds__(256) zero_deg(int* __restrict__ deg){
  deg[blockIdx.x * 256 + threadIdx.x] = 0;   // grid = NNODES/256
}

__global__ void __launch_bounds__(256) count_deg(const int* __restrict__ ei, int* __restrict__ deg){
  int i = blockIdx.x * 256 + threadIdx.x;    // grid exactly NETOT/256
  int d = (i < NEDGES) ? ei[NEDGES + i] : (i - NEDGES);
  atomicAdd(&deg[d], 1);
}

// single block; row_off[0..N] and cursor[i] = row start
__global__ void __launch_bounds__(1024) scan_deg(const int* __restrict__ deg,
                                                 int* __restrict__ row_off,
                                                 int* __restrict__ cursor){
  __shared__ int wsum[16];
  __shared__ int woff[16];
  __shared__ int carry_s;
  const int tid = threadIdx.x, lane = tid & 63, w = tid >> 6;
  if(tid == 0){ carry_s = 0; row_off[0] = 0; }
  __syncthreads();
  for(int base = 0; base < NNODES; base += 1024){
    int v = deg[base + tid];
    int x = v;
    #pragma unroll
    for(int o = 1; o < 64; o <<= 1){ int u = __shfl_up(x, o, 64); if(lane >= o) x += u; }
    if(lane == 63) wsum[w] = x;
    __syncthreads();
    if(w == 0){
      int t0 = (lane < 16) ? wsum[lane] : 0;
      int y = t0;
      #pragma unroll
      for(int o = 1; o < 16; o <<= 1){ int u = __shfl_up(y, o, 64); if(lane >= o) y += u; }
      if(lane < 16) woff[lane] = y - t0;   // exclusive among waves
    }
    __syncthreads();
    int carry = carry_s;
    int incl = carry + woff[w] + x;
    row_off[base + tid + 1] = incl;
    cursor[base + tid] = incl - v;
    __syncthreads();
    if(tid == 1023) carry_s = incl;
    __syncthreads();
  }
}

__global__ void __launch_bounds__(256) fill_csr(const int* __restrict__ ei, int* __restrict__ cursor,
                                                int* __restrict__ col_src){
  int i = blockIdx.x * 256 + threadIdx.x;  // grid exactly NETOT/256
  int s, d;
  if(i < NEDGES){ s = ei[i]; d = ei[NEDGES + i]; }
  else          { s = i - NEDGES; d = s; }
  int p = atomicAdd(&cursor[d], 1);
  col_src[p] = s;
}

// ---------------- conversions ----------------
__global__ void __launch_bounds__(256) convX(const float* __restrict__ x, unsigned short* __restrict__ xb){
  int i = blockIdx.x * 256 + threadIdx.x;
  xb[i] = f2b(x[i]);
}

// W (fp32 [K][256] x2) -> Wt bf16 [512][2K], transposed; hi plane at k, lo plane at K+k
template<int K>
__global__ void __launch_bounds__(256) convW(const float* __restrict__ Wl, const float* __restrict__ Wr,
                                             unsigned short* __restrict__ Wt){
  int i = blockIdx.x * 256 + threadIdx.x;        // grid = K*512/256
  int k = i >> 9, c = i & 511;
  float val = (c < 256) ? Wl[(size_t)k * 256 + c] : Wr[(size_t)k * 256 + (c - 256)];
  unsigned short hi = f2b(val);
  unsigned short lo = f2b(val - b2f(hi));
  Wt[(size_t)c * (2 * K) + k]     = hi;
  Wt[(size_t)c * (2 * K) + K + k] = lo;
}

// ---------------- GEMM: xlb[N][512](bf16) = A[N][K](bf16) @ W(fp32 via hi/lo planes) ----------------
// tile 128x128, 4 waves, 16 MFMA per wave per 32-k step.
// MFMA 16x16x32_bf16; C/D: col=lane&15, row=(lane>>4)*4+reg
template<int K>
__global__ void __launch_bounds__(256) gemm_xw(const unsigned short* __restrict__ A,
                                               const unsigned short* __restrict__ Wt,
                                               unsigned short* __restrict__ Cout){
  __shared__ unsigned short As[128][40];  // BK=32, padded row stride 80 B
  __shared__ unsigned short Bs[128][40];
  const int t = threadIdx.x;
  const int rowbase = blockIdx.x * 128;
  const int colbase = blockIdx.y * 128;
  const int wave = t >> 6, lane = t & 63;
  const int lrow = lane & 15, kg = lane >> 4;

  f32x4 acc[2][8] = {};

  for(int kt = 0; kt < 2 * K; kt += 32){
    const int ka = kt & (K - 1);       // A re-read for hi (k<K) and lo (k>=K) W planes
    { // stage A: 128 rows x 32 k
      int oct = t & 3, r = t >> 2;
      const unsigned short* ga = A + (size_t)(rowbase + r) * K + ka + oct * 8;
      short8 v0 = *(const short8*)ga;
      short8 v1 = *(const short8*)(ga + 64 * K);
      *(short8*)(&As[r][oct * 8])      = v0;
      *(short8*)(&As[r + 64][oct * 8]) = v1;
    }
    { // stage B: Bs[n][k] = Wt[colbase+n][kt+k]; n = t&127, k-half = (t>>7)*16
      int n = t & 127, kh = (t >> 7) * 16;
      const unsigned short* gw = Wt + (size_t)(colbase + n) * (2 * K) + kt + kh;
      short8 v0 = *(const short8*)gw;
      short8 v1 = *(const short8*)(gw + 8);
      *(short8*)(&Bs[n][kh])     = v0;
      *(short8*)(&Bs[n][kh + 8]) = v1;
    }
    __syncthreads();
    short8 afrag[2], bfrag[8];
    afrag[0] = *(const short8*)(&As[wave * 32 + lrow][kg * 8]);
    afrag[1] = *(const short8*)(&As[wave * 32 + 16 + lrow][kg * 8]);
    #pragma unroll
    for(int fc = 0; fc < 8; fc++) bfrag[fc] = *(const short8*)(&Bs[fc * 16 + lrow][kg * 8]);
    #pragma unroll
    for(int rf = 0; rf < 2; rf++)
      #pragma unroll
      for(int fc = 0; fc < 8; fc++)
        acc[rf][fc] = __builtin_amdgcn_mfma_f32_16x16x32_bf16(afrag[rf], bfrag[fc], acc[rf][fc], 0, 0, 0);
    __syncthreads();
  }
  #pragma unroll
  for(int rf = 0; rf < 2; rf++)
    #pragma unroll
    for(int fc = 0; fc < 8; fc++)
      #pragma unroll
      for(int r = 0; r < 4; r++){
        int row = rowbase + wave * 32 + rf * 16 + kg * 4 + r;
        int col = colbase + fc * 16 + lrow;
        Cout[(size_t)row * 512 + col] = f2b(acc[rf][fc][r]);
      }
}

// ---------------- per-dst-node softmax aggregation (bf16 gather) ----------------
// one wave per dst node. lane = eg*32 + (hg*16 + l16); lane owns 8 channels
// c0=(lane&31)*8 (covers both heads), eg = edge parity -> 2 edges in flight.
// 16-lane dot groups: 4-stage shfl_xor reduce. No max-subtraction (|logit| ~ 5).
__global__ void __launch_bounds__(256) edge_agg(const unsigned short* __restrict__ xlb,
                                                const int* __restrict__ row_off,
                                                const int* __restrict__ col_src,
                                                const float* __restrict__ att,
                                                const float* __restrict__ bias,
                                                unsigned short* __restrict__ hout){
  const int n = (blockIdx.x * 256 + threadIdx.x) >> 6;
  const int lane = threadIdx.x & 63;
  const int eg = lane >> 5;
  const int c0 = (lane & 31) * 8;
  float xr[8], at[8];
  {
    const unsigned short* xp = xlb + (size_t)n * 512 + 256 + c0;   // Wr x_dst
    ushort4 v0 = *(const ushort4*)xp, v1 = *(const ushort4*)(xp + 4);
    xr[0] = b2f(v0.x); xr[1] = b2f(v0.y); xr[2] = b2f(v0.z); xr[3] = b2f(v0.w);
    xr[4] = b2f(v1.x); xr[5] = b2f(v1.y); xr[6] = b2f(v1.z); xr[7] = b2f(v1.w);
    #pragma unroll
    for(int i = 0; i < 8; i++) at[i] = att[c0 + i];
  }
  float s = 0.f;
  float ac[8] = {};
  const int beg = row_off[n], end = row_off[n + 1];
  for(int ch = beg; ch < end; ch += 64){
    int idx = ch + lane;
    int si = (idx < end) ? col_src[idx] : 0;
    int cnt = end - ch; if(cnt > 64) cnt = 64;
    for(int k = 0; k < cnt; k += 2){
      int kk = k + eg;
      bool valid = kk < cnt;
      int src = __shfl(si, kk & 63);
      const unsigned short* gp = xlb + (size_t)src * 512 + c0;     // Wl x_src
      ushort4 v0 = *(const ushort4*)gp, v1 = *(const ushort4*)(gp + 4);
      float x0 = b2f(v0.x), x1 = b2f(v0.y), x2 = b2f(v0.z), x3 = b2f(v0.w);
      float x4 = b2f(v1.x), x5 = b2f(v1.y), x6 = b2f(v1.z), x7 = b2f(v1.w);
      float e, p;
      e = x0 + xr[0]; e = fmaxf(e, 0.2f * e); p = at[0] * e;
      e = x1 + xr[1]; e = fmaxf(e, 0.2f * e); p = fmaf(at[1], e, p);
      e = x2 + xr[2]; e = fmaxf(e, 0.2f * e); p = fmaf(at[2], e, p);
      e = x3 + xr[3]; e = fmaxf(e, 0.2f * e); p = fmaf(at[3], e, p);
      e = x4 + xr[4]; e = fmaxf(e, 0.2f * e); p = fmaf(at[4], e, p);
      e = x5 + xr[5]; e = fmaxf(e, 0.2f * e); p = fmaf(at[5], e, p);
      e = x6 + xr[6]; e = fmaxf(e, 0.2f * e); p = fmaf(at[6], e, p);
      e = x7 + xr[7]; e = fmaxf(e, 0.2f * e); p = fmaf(at[7], e, p);
      p += __shfl_xor(p, 1); p += __shfl_xor(p, 2);
      p += __shfl_xor(p, 4); p += __shfl_xor(p, 8);    // per-(edge,head) 16-lane reduce
      float pe = valid ? __expf(p) : 0.f;
      s += pe;
      ac[0] = fmaf(pe, x0, ac[0]); ac[1] = fmaf(pe, x1, ac[1]);
      ac[2] = fmaf(pe, x2, ac[2]); ac[3] = fmaf(pe, x3, ac[3]);
      ac[4] = fmaf(pe, x4, ac[4]); ac[5] = fmaf(pe, x5, ac[5]);
      ac[6] = fmaf(pe, x6, ac[6]); ac[7] = fmaf(pe, x7, ac[7]);
    }
  }
  // combine the two edge-parity halves (lane ^ 32)
  s += __shfl_xor(s, 32);
  #pragma unroll
  for(int i = 0; i < 8; i++) ac[i] += __shfl_xor(ac[i], 32);
  if(eg == 0){
    float inv = 1.f / s;
    ushort4 o0, o1;
    o0.x = f2b(fmaf(ac[0], inv, bias[c0 + 0]));
    o0.y = f2b(fmaf(ac[1], inv, bias[c0 + 1]));
    o0.z = f2b(fmaf(ac[2], inv, bias[c0 + 2]));
    o0.w = f2b(fmaf(ac[3], inv, bias[c0 + 3]));
    o1.x = f2b(fmaf(ac[4], inv, bias[c0 + 4]));
    o1.y = f2b(fmaf(ac[5], inv, bias[c0 + 5]));
    o1.z = f2b(fmaf(ac[6], inv, bias[c0 + 6]));
    o1.w = f2b(fmaf(ac[7], inv, bias[c0 + 7]));
    *(ushort4*)(hout + (size_t)n * 256 + c0)     = o0;
    *(ushort4*)(hout + (size_t)n * 256 + c0 + 4) = o1;
  }
}

// ---------------- pooling (node-parallel x8) ----------------
__device__ __forceinline__ int lbound(const int* __restrict__ a, int n, int v){
  int lo = 0, hi = n;
  while(lo < hi){ int mid = (lo + hi) >> 1; if(a[mid] < v) lo = mid + 1; else hi = mid; }
  return lo;
}

__global__ void __launch_bounds__(256) pool_accum(const unsigned short* __restrict__ h,
                                                  const int* __restrict__ batch,
                                                  float* __restrict__ pool, int slot){
  __shared__ float red[8][264];
  const int g = blockIdx.x, t = threadIdx.x;
  const int ng = t >> 5, c0 = (t & 31) * 8;
  const int lo = lbound(batch, NNODES, g);
  const int hi = lbound(batch, NNODES, g + 1);
  float a[8] = {};
  for(int node = lo + ng; node < hi; node += 8){
    const unsigned short* hp = h + (size_t)node * 256 + c0;
    ushort4 v0 = *(const ushort4*)hp, v1 = *(const ushort4*)(hp + 4);
    a[0] += b2f(v0.x); a[1] += b2f(v0.y); a[2] += b2f(v0.z); a[3] += b2f(v0.w);
    a[4] += b2f(v1.x); a[5] += b2f(v1.y); a[6] += b2f(v1.z); a[7] += b2f(v1.w);
  }
  #pragma unroll
  for(int i = 0; i < 8; i++) red[ng][c0 + i] = a[i];
  __syncthreads();
  float s = 0.f;
  #pragma unroll
  for(int i = 0; i < 8; i++) s += red[i][t];
  pool[(size_t)g * 768 + slot * 256 + t] = s;
}

// ---------------- FFN ----------------
// hidden[256][768] = relu(pool @ fW1 + fb1); tile 32 cols x 32 graphs, LDS-staged
__global__ void __launch_bounds__(256) ffn1(const float* __restrict__ pool,
                                            const float* __restrict__ fW1,
                                            const float* __restrict__ fb1,
                                            float* __restrict__ hidden){
  __shared__ float ap[32][65];   // [graph][k]
  __shared__ float ws[64][33];   // [k][col]
  const int t = threadIdx.x;
  const int cb = blockIdx.x * 32;
  const int gb = blockIdx.y * 32;
  const int tc = t & 31, tg = t >> 5;    // tg 0..7 -> 4 graphs each
  float acc[4] = {};
  for(int kc = 0; kc < 768; kc += 64){
    {
      int g_l = t >> 3, j8 = (t & 7) * 8;
      const float* gp = pool + (size_t)(gb + g_l) * 768 + kc + j8;
      #pragma unroll
      for(int i = 0; i < 8; i++) ap[g_l][j8 + i] = gp[i];
    }
    {
      int c_l = t & 31, k0 = (t >> 5) * 8;
      #pragma unroll
      for(int i = 0; i < 8; i++) ws[k0 + i][c_l] = fW1[(size_t)(kc + k0 + i) * 768 + cb + c_l];
    }
    __syncthreads();
    #pragma unroll
    for(int k = 0; k < 64; k++){
      float w = ws[k][tc];
      #pragma unroll
      for(int i = 0; i < 4; i++) acc[i] = fmaf(ap[tg * 4 + i][k], w, acc[i]);
    }
    __syncthreads();
  }
  float b = fb1[cb + tc];
  #pragma unroll
  for(int i = 0; i < 4; i++)
    hidden[(size_t)(gb + tg * 4 + i) * 768 + cb + tc] = fmaxf(acc[i] + b, 0.f);
}

__global__ void __launch_bounds__(256) ffn2(const float* __restrict__ hidden,
                                            const float* __restrict__ fW2,
                                            const float* __restrict__ fb2,
                                            float* __restrict__ out){
  const int g = (blockIdx.x * 256 + threadIdx.x) >> 6;   // one wave per graph
  const int lane = threadIdx.x & 63;
  float p = 0.f;
  for(int i = lane; i < 768; i += 64) p += hidden[(size_t)g * 768 + i] * fW2[i];
  #pragma unroll
  for(int o = 32; o > 0; o >>= 1) p += __shfl_xor(p, o, 64);
  if(lane == 0) out[g] = p + fb2[0];
}

extern "C" void kernel_launch(void* const* d_in, const int* in_sizes, int n_in,
                              void* d_out, int out_size, void* d_ws, size_t ws_size,
                              hipStream_t stream){
  const float* x    = (const float*)d_in[0];
  const int* ei     = (const int*)d_in[1];
  const int* batch  = (const int*)d_in[2];
  const float* Wl[3]  = {(const float*)d_in[3],  (const float*)d_in[7],  (const float*)d_in[11]};
  const float* Wr[3]  = {(const float*)d_in[4],  (const float*)d_in[8],  (const float*)d_in[12]};
  const float* att[3] = {(const float*)d_in[5],  (const float*)d_in[9],  (const float*)d_in[13]};
  const float* bp[3]  = {(const float*)d_in[6],  (const float*)d_in[10], (const float*)d_in[14]};
  const float* fW1 = (const float*)d_in[15];
  const float* fb1 = (const float*)d_in[16];
  const float* fW2 = (const float*)d_in[17];
  const float* fb2 = (const float*)d_in[18];

  char* ws = (char*)d_ws;
  size_t off = 0;
  auto alloc = [&](size_t sz){ size_t p = off; off += (sz + 255) & ~(size_t)255; return p; };
  int* deg      = (int*)(ws + alloc((size_t)NNODES * 4));
  int* rowoff   = (int*)(ws + alloc((size_t)(NNODES + 1) * 4));
  int* cursor   = (int*)(ws + alloc((size_t)NNODES * 4));
  int* colsrc   = (int*)(ws + alloc((size_t)NETOT * 4));
  unsigned short* xb  = (unsigned short*)(ws + alloc((size_t)NNODES * 128 * 2));
  unsigned short* Wt  = (unsigned short*)(ws + alloc((size_t)512 * 512 * 2));
  unsigned short* xlb = (unsigned short*)(ws + alloc((size_t)NNODES * 512 * 2));
  unsigned short* hA  = (unsigned short*)(ws + alloc((size_t)NNODES * 256 * 2));
  unsigned short* hB  = (unsigned short*)(ws + alloc((size_t)NNODES * 256 * 2));
  float* pool   = (float*)(ws + alloc((size_t)NGRAPH * 768 * 4));
  float* hidden = (float*)(ws + alloc((size_t)NGRAPH * 768 * 4));

  // CSR build
  zero_deg<<<NNODES / 256, 256, 0, stream>>>(deg);
  count_deg<<<NETOT / 256, 256, 0, stream>>>(ei, deg);
  scan_deg<<<1, 1024, 0, stream>>>(deg, rowoff, cursor);
  fill_csr<<<NETOT / 256, 256, 0, stream>>>(ei, cursor, colsrc);

  dim3 ggrid(NNODES / 128, 4);

  // layer 1 (K=128)
  convX<<<NNODES * 128 / 256, 256, 0, stream>>>(x, xb);
  convW<128><<<128 * 512 / 256, 256, 0, stream>>>(Wl[0], Wr[0], Wt);
  gemm_xw<128><<<ggrid, 256, 0, stream>>>(xb, Wt, xlb);
  edge_agg<<<NNODES / 4, 256, 0, stream>>>(xlb, rowoff, colsrc, att[0], bp[0], hA);
  pool_accum<<<NGRAPH, 256, 0, stream>>>(hA, batch, pool, 0);

  // layer 2 (K=256)
  convW<256><<<256 * 512 / 256, 256, 0, stream>>>(Wl[1], Wr[1], Wt);
  gemm_xw<256><<<ggrid, 256, 0, stream>>>(hA, Wt, xlb);
  edge_agg<<<NNODES / 4, 256, 0, stream>>>(xlb, rowoff, colsrc, att[1], bp[1], hB);
  pool_accum<<<NGRAPH, 256, 0, stream>>>(hB, batch, pool, 1);

  // layer 3 (K=256)
  convW<256><<<256 * 512 / 256, 256, 0, stream>>>(Wl[2], Wr[2], Wt);
  gemm_xw<256><<<ggrid, 256, 0, stream>>>(hB, Wt, xlb);
  edge_agg<<<NNODES / 4, 256, 0, stream>>>(xlb, rowoff, colsrc, att[2], bp[2], hA);
  pool_accum<<<NGRAPH, 256, 0, stream>>>(hA, batch, pool, 2);

  // FFN head
  ffn1<<<dim3(768 / 32, NGRAPH / 32), 256, 0, stream>>>(pool, fW1, fb1, hidden);
  ffn2<<<NGRAPH / 4, 256, 0, stream>>>(hidden, fW2, fb2, (float*)d_out);
}

// Round 6
// 290.142 us; speedup vs baseline: 1.8194x; 1.0970x over previous
//
#include <hip/hip_runtime.h>

#define NNODES 16384
#define NEDGES 524288
#define NETOT  (NEDGES + NNODES)   // 540672 (self-loops appended)
#define NGRAPH 256

typedef __attribute__((ext_vector_type(8))) short short8;
typedef __attribute__((ext_vector_type(4))) float f32x4;
typedef __attribute__((ext_vector_type(2))) float f32x2;

__device__ __forceinline__ float b2f(unsigned short u){
  union { unsigned int i; float f; } v; v.i = ((unsigned int)u) << 16; return v.f;
}
__device__ __forceinline__ unsigned short f2b(float f){
  union { float f; unsigned int i; } v; v.f = f;
  unsigned int r = v.i + 0x7FFFu + ((v.i >> 16) & 1u);
  return (unsigned short)(r >> 16);
}
// unpack 2 bf16 (packed in one u32: ch i low half, ch i+1 high half) -> f32x2
__device__ __forceinline__ f32x2 unpack2(unsigned int u){
  union { unsigned int i; float f; } lo, hi;
  lo.i = u << 16; hi.i = u & 0xFFFF0000u;
  f32x2 r; r[0] = lo.f; r[1] = hi.f; return r;
}

// ---------------- CSR build (dst-sorted) ----------------
__global__ void __launch_bounds__(256) zero_deg(int* __restrict__ deg){
  deg[blockIdx.x * 256 + threadIdx.x] = 0;   // grid = NNODES/256
}

__global__ void __launch_bounds__(256) count_deg(const int* __restrict__ ei, int* __restrict__ deg){
  int i = blockIdx.x * 256 + threadIdx.x;    // grid exactly NETOT/256
  int d = (i < NEDGES) ? ei[NEDGES + i] : (i - NEDGES);
  atomicAdd(&deg[d], 1);
}

// phase 1: per-block (256-elem) inclusive scan + block sums. grid = NNODES/256
__global__ void __launch_bounds__(256) scan1(const int* __restrict__ deg,
                                             int* __restrict__ incl, int* __restrict__ bsum){
  __shared__ int ws[4];
  const int b = blockIdx.x, t = threadIdx.x, lane = t & 63, w = t >> 6;
  int v = deg[b * 256 + t];
  int x = v;
  #pragma unroll
  for(int o = 1; o < 64; o <<= 1){ int u = __shfl_up(x, o, 64); if(lane >= o) x += u; }
  if(lane == 63) ws[w] = x;
  __syncthreads();
  int add = 0;
  #pragma unroll
  for(int j = 0; j < 4; j++) if(j < w) add += ws[j];
  incl[b * 256 + t] = x + add;
  if(t == 255) bsum[b] = x + add;
}

// phase 2: exclusive scan of 64 block sums (1 block, 64 threads = 1 wave)
__global__ void __launch_bounds__(64) scan2(const int* __restrict__ bsum, int* __restrict__ boff){
  const int t = threadIdx.x;
  int v = bsum[t];
  int x = v;
  #pragma unroll
  for(int o = 1; o < 64; o <<= 1){ int u = __shfl_up(x, o, 64); if(t >= o) x += u; }
  boff[t] = x - v;
}

// phase 3: apply offsets -> row_off / cursor. grid = NNODES/256
__global__ void __launch_bounds__(256) scan3(const int* __restrict__ deg, const int* __restrict__ incl,
                                             const int* __restrict__ boff,
                                             int* __restrict__ row_off, int* __restrict__ cursor){
  const int b = blockIdx.x, t = threadIdx.x;
  const int i = b * 256 + t;
  int inc = incl[i] + boff[b];
  row_off[i + 1] = inc;
  cursor[i] = inc - deg[i];
  if(i == 0) row_off[0] = 0;
}

__global__ void __launch_bounds__(256) fill_csr(const int* __restrict__ ei, int* __restrict__ cursor,
                                                int* __restrict__ col_src){
  int i = blockIdx.x * 256 + threadIdx.x;  // grid exactly NETOT/256
  int s, d;
  if(i < NEDGES){ s = ei[i]; d = ei[NEDGES + i]; }
  else          { s = i - NEDGES; d = s; }
  int p = atomicAdd(&cursor[d], 1);
  col_src[p] = s;
}

// ---------------- conversions ----------------
__global__ void __launch_bounds__(256) convX(const float* __restrict__ x, unsigned short* __restrict__ xb){
  int i = blockIdx.x * 256 + threadIdx.x;
  xb[i] = f2b(x[i]);
}

// W (fp32 [K][256] x2) -> Wt bf16 [512][K] transposed (single plane)
template<int K>
__global__ void __launch_bounds__(256) convW(const float* __restrict__ Wl, const float* __restrict__ Wr,
                                             unsigned short* __restrict__ Wt){
  int i = blockIdx.x * 256 + threadIdx.x;        // grid = K*512/256
  int k = i >> 9, c = i & 511;
  float val = (c < 256) ? Wl[(size_t)k * 256 + c] : Wr[(size_t)k * 256 + (c - 256)];
  Wt[(size_t)c * K + k] = f2b(val);
}

// ---------------- GEMM: xlb[N][512](bf16) = A[N][K](bf16) @ Wt^T ----------------
// tile 128x128, 4 waves, 16 MFMA per wave per 32-k step.
// MFMA 16x16x32_bf16; C/D: col=lane&15, row=(lane>>4)*4+reg
template<int K>
__global__ void __launch_bounds__(256) gemm_xw(const unsigned short* __restrict__ A,
                                               const unsigned short* __restrict__ Wt,
                                               unsigned short* __restrict__ Cout){
  __shared__ unsigned short As[128][40];  // BK=32, padded row stride 80 B
  __shared__ unsigned short Bs[128][40];
  const int t = threadIdx.x;
  const int rowbase = blockIdx.x * 128;
  const int colbase = blockIdx.y * 128;
  const int wave = t >> 6, lane = t & 63;
  const int lrow = lane & 15, kg = lane >> 4;

  f32x4 acc[2][8] = {};

  for(int kt = 0; kt < K; kt += 32){
    { // stage A: 128 rows x 32 k
      int oct = t & 3, r = t >> 2;
      const unsigned short* ga = A + (size_t)(rowbase + r) * K + kt + oct * 8;
      short8 v0 = *(const short8*)ga;
      short8 v1 = *(const short8*)(ga + 64 * K);
      *(short8*)(&As[r][oct * 8])      = v0;
      *(short8*)(&As[r + 64][oct * 8]) = v1;
    }
    { // stage B: Bs[n][k] = Wt[colbase+n][kt+k]; n = t&127, k-half = (t>>7)*16
      int n = t & 127, kh = (t >> 7) * 16;
      const unsigned short* gw = Wt + (size_t)(colbase + n) * K + kt + kh;
      short8 v0 = *(const short8*)gw;
      short8 v1 = *(const short8*)(gw + 8);
      *(short8*)(&Bs[n][kh])     = v0;
      *(short8*)(&Bs[n][kh + 8]) = v1;
    }
    __syncthreads();
    short8 afrag[2], bfrag[8];
    afrag[0] = *(const short8*)(&As[wave * 32 + lrow][kg * 8]);
    afrag[1] = *(const short8*)(&As[wave * 32 + 16 + lrow][kg * 8]);
    #pragma unroll
    for(int fc = 0; fc < 8; fc++) bfrag[fc] = *(const short8*)(&Bs[fc * 16 + lrow][kg * 8]);
    #pragma unroll
    for(int rf = 0; rf < 2; rf++)
      #pragma unroll
      for(int fc = 0; fc < 8; fc++)
        acc[rf][fc] = __builtin_amdgcn_mfma_f32_16x16x32_bf16(afrag[rf], bfrag[fc], acc[rf][fc], 0, 0, 0);
    __syncthreads();
  }
  #pragma unroll
  for(int rf = 0; rf < 2; rf++)
    #pragma unroll
    for(int fc = 0; fc < 8; fc++)
      #pragma unroll
      for(int r = 0; r < 4; r++){
        int row = rowbase + wave * 32 + rf * 16 + kg * 4 + r;
        int col = colbase + fc * 16 + lrow;
        Cout[(size_t)row * 512 + col] = f2b(acc[rf][fc][r]);
      }
}

// ---------------- per-dst-node softmax aggregation (packed f32x2 math) ----------------
// one wave per dst node. lane = eg*32 + l; lane owns 8 channels c0=(lane&31)*8
// (covers both heads: lanes 0-15 head0, 16-31 head1 per parity), eg = edge parity.
// 16-lane dot groups -> 4-stage shfl_xor reduce. No max-subtraction (|logit| small).
__global__ void __launch_bounds__(256) edge_agg(const unsigned short* __restrict__ xlb,
                                                const int* __restrict__ row_off,
                                                const int* __restrict__ col_src,
                                                const float* __restrict__ att,
                                                const float* __restrict__ bias,
                                                unsigned short* __restrict__ hout){
  const int n = (blockIdx.x * 256 + threadIdx.x) >> 6;
  const int lane = threadIdx.x & 63;
  const int eg = lane >> 5;
  const int c0 = (lane & 31) * 8;
  f32x2 xr0, xr1, xr2, xr3, at0, at1, at2, at3;
  {
    uint4 v = *(const uint4*)(xlb + (size_t)n * 512 + 256 + c0);   // Wr x_dst
    xr0 = unpack2(v.x); xr1 = unpack2(v.y); xr2 = unpack2(v.z); xr3 = unpack2(v.w);
    at0 = *(const f32x2*)(att + c0);
    at1 = *(const f32x2*)(att + c0 + 2);
    at2 = *(const f32x2*)(att + c0 + 4);
    at3 = *(const f32x2*)(att + c0 + 6);
  }
  float s = 0.f;
  f32x2 ac0 = {0.f, 0.f}, ac1 = {0.f, 0.f}, ac2 = {0.f, 0.f}, ac3 = {0.f, 0.f};
  const int beg = row_off[n], end = row_off[n + 1];
  for(int ch = beg; ch < end; ch += 64){
    int idx = ch + lane;
    int si = (idx < end) ? col_src[idx] : 0;
    int cnt = end - ch; if(cnt > 64) cnt = 64;
    for(int k = 0; k < cnt; k += 2){
      int kk = k + eg;
      int src = __shfl(si, kk);
      uint4 v = *(const uint4*)(xlb + (size_t)src * 512 + c0);     // Wl x_src (16B)
      f32x2 x0 = unpack2(v.x), x1 = unpack2(v.y), x2 = unpack2(v.z), x3 = unpack2(v.w);
      f32x2 e0 = x0 + xr0, e1 = x1 + xr1, e2 = x2 + xr2, e3 = x3 + xr3;
      e0 = __builtin_elementwise_max(e0, e0 * 0.2f);
      e1 = __builtin_elementwise_max(e1, e1 * 0.2f);
      e2 = __builtin_elementwise_max(e2, e2 * 0.2f);
      e3 = __builtin_elementwise_max(e3, e3 * 0.2f);
      f32x2 p2 = e0 * at0;
      p2 += e1 * at1;
      p2 += e2 * at2;
      p2 += e3 * at3;
      float p = p2[0] + p2[1];
      p += __shfl_xor(p, 1); p += __shfl_xor(p, 2);
      p += __shfl_xor(p, 4); p += __shfl_xor(p, 8);    // per-(edge,head) 16-lane reduce
      float pe = (kk < cnt) ? __expf(p) : 0.f;
      s += pe;
      f32x2 pe2 = {pe, pe};
      ac0 += pe2 * x0; ac1 += pe2 * x1; ac2 += pe2 * x2; ac3 += pe2 * x3;
    }
  }
  // combine the two edge-parity halves (lane ^ 32)
  s += __shfl_xor(s, 32);
  #pragma unroll
  for(int i = 0; i < 2; i++){
    ac0[i] += __shfl_xor(ac0[i], 32); ac1[i] += __shfl_xor(ac1[i], 32);
    ac2[i] += __shfl_xor(ac2[i], 32); ac3[i] += __shfl_xor(ac3[i], 32);
  }
  if(eg == 0){
    float inv = 1.f / s;
    ushort4 o0, o1;
    o0.x = f2b(fmaf(ac0[0], inv, bias[c0 + 0]));
    o0.y = f2b(fmaf(ac0[1], inv, bias[c0 + 1]));
    o0.z = f2b(fmaf(ac1[0], inv, bias[c0 + 2]));
    o0.w = f2b(fmaf(ac1[1], inv, bias[c0 + 3]));
    o1.x = f2b(fmaf(ac2[0], inv, bias[c0 + 4]));
    o1.y = f2b(fmaf(ac2[1], inv, bias[c0 + 5]));
    o1.z = f2b(fmaf(ac3[0], inv, bias[c0 + 6]));
    o1.w = f2b(fmaf(ac3[1], inv, bias[c0 + 7]));
    *(ushort4*)(hout + (size_t)n * 256 + c0)     = o0;
    *(ushort4*)(hout + (size_t)n * 256 + c0 + 4) = o1;
  }
}

// ---------------- pooling (node-parallel x8) ----------------
__device__ __forceinline__ int lbound(const int* __restrict__ a, int n, int v){
  int lo = 0, hi = n;
  while(lo < hi){ int mid = (lo + hi) >> 1; if(a[mid] < v) lo = mid + 1; else hi = mid; }
  return lo;
}

__global__ void __launch_bounds__(256) pool_accum(const unsigned short* __restrict__ h,
                                                  const int* __restrict__ batch,
                                                  float* __restrict__ pool, int slot){
  __shared__ float red[8][264];
  const int g = blockIdx.x, t = threadIdx.x;
  const int ng = t >> 5, c0 = (t & 31) * 8;
  const int lo = lbound(batch, NNODES, g);
  const int hi = lbound(batch, NNODES, g + 1);
  f32x2 a0 = {0.f,0.f}, a1 = {0.f,0.f}, a2 = {0.f,0.f}, a3 = {0.f,0.f};
  for(int node = lo + ng; node < hi; node += 8){
    uint4 v = *(const uint4*)(h + (size_t)node * 256 + c0);
    a0 += unpack2(v.x); a1 += unpack2(v.y); a2 += unpack2(v.z); a3 += unpack2(v.w);
  }
  red[ng][c0 + 0] = a0[0]; red[ng][c0 + 1] = a0[1];
  red[ng][c0 + 2] = a1[0]; red[ng][c0 + 3] = a1[1];
  red[ng][c0 + 4] = a2[0]; red[ng][c0 + 5] = a2[1];
  red[ng][c0 + 6] = a3[0]; red[ng][c0 + 7] = a3[1];
  __syncthreads();
  float s = 0.f;
  #pragma unroll
  for(int i = 0; i < 8; i++) s += red[i][t];
  pool[(size_t)g * 768 + slot * 256 + t] = s;
}

// ---------------- FFN ----------------
// hidden[256][768] = relu(pool @ fW1 + fb1); tile 32 cols x 32 graphs, LDS-staged
__global__ void __launch_bounds__(256) ffn1(const float* __restrict__ pool,
                                            const float* __restrict__ fW1,
                                            const float* __restrict__ fb1,
                                            float* __restrict__ hidden){
  __shared__ float ap[32][65];   // [graph][k]
  __shared__ float ws[64][33];   // [k][col]
  const int t = threadIdx.x;
  const int cb = blockIdx.x * 32;
  const int gb = blockIdx.y * 32;
  const int tc = t & 31, tg = t >> 5;    // tg 0..7 -> 4 graphs each
  float acc[4] = {};
  for(int kc = 0; kc < 768; kc += 64){
    {
      int g_l = t >> 3, j8 = (t & 7) * 8;
      const float* gp = pool + (size_t)(gb + g_l) * 768 + kc + j8;
      #pragma unroll
      for(int i = 0; i < 8; i++) ap[g_l][j8 + i] = gp[i];
    }
    {
      int c_l = t & 31, k0 = (t >> 5) * 8;
      #pragma unroll
      for(int i = 0; i < 8; i++) ws[k0 + i][c_l] = fW1[(size_t)(kc + k0 + i) * 768 + cb + c_l];
    }
    __syncthreads();
    #pragma unroll
    for(int k = 0; k < 64; k++){
      float w = ws[k][tc];
      #pragma unroll
      for(int i = 0; i < 4; i++) acc[i] = fmaf(ap[tg * 4 + i][k], w, acc[i]);
    }
    __syncthreads();
  }
  float b = fb1[cb + tc];
  #pragma unroll
  for(int i = 0; i < 4; i++)
    hidden[(size_t)(gb + tg * 4 + i) * 768 + cb + tc] = fmaxf(acc[i] + b, 0.f);
}

__global__ void __launch_bounds__(256) ffn2(const float* __restrict__ hidden,
                                            const float* __restrict__ fW2,
                                            const float* __restrict__ fb2,
                                            float* __restrict__ out){
  const int g = (blockIdx.x * 256 + threadIdx.x) >> 6;   // one wave per graph
  const int lane = threadIdx.x & 63;
  float p = 0.f;
  for(int i = lane; i < 768; i += 64) p += hidden[(size_t)g * 768 + i] * fW2[i];
  #pragma unroll
  for(int o = 32; o > 0; o >>= 1) p += __shfl_xor(p, o, 64);
  if(lane == 0) out[g] = p + fb2[0];
}

extern "C" void kernel_launch(void* const* d_in, const int* in_sizes, int n_in,
                              void* d_out, int out_size, void* d_ws, size_t ws_size,
                              hipStream_t stream){
  const float* x    = (const float*)d_in[0];
  const int* ei     = (const int*)d_in[1];
  const int* batch  = (const int*)d_in[2];
  const float* Wl[3]  = {(const float*)d_in[3],  (const float*)d_in[7],  (const float*)d_in[11]};
  const float* Wr[3]  = {(const float*)d_in[4],  (const float*)d_in[8],  (const float*)d_in[12]};
  const float* att[3] = {(const float*)d_in[5],  (const float*)d_in[9],  (const float*)d_in[13]};
  const float* bp[3]  = {(const float*)d_in[6],  (const float*)d_in[10], (const float*)d_in[14]};
  const float* fW1 = (const float*)d_in[15];
  const float* fb1 = (const float*)d_in[16];
  const float* fW2 = (const float*)d_in[17];
  const float* fb2 = (const float*)d_in[18];

  char* ws = (char*)d_ws;
  size_t off = 0;
  auto alloc = [&](size_t sz){ size_t p = off; off += (sz + 255) & ~(size_t)255; return p; };
  int* deg      = (int*)(ws + alloc((size_t)NNODES * 4));
  int* rowoff   = (int*)(ws + alloc((size_t)(NNODES + 1) * 4));
  int* cursor   = (int*)(ws + alloc((size_t)NNODES * 4));
  int* colsrc   = (int*)(ws + alloc((size_t)NETOT * 4));
  int* incl     = (int*)(ws + alloc((size_t)NNODES * 4));
  int* bsum     = (int*)(ws + alloc(64 * 4));
  int* boff     = (int*)(ws + alloc(64 * 4));
  unsigned short* xb  = (unsigned short*)(ws + alloc((size_t)NNODES * 128 * 2));
  unsigned short* Wt  = (unsigned short*)(ws + alloc((size_t)512 * 256 * 2));   // max K=256
  unsigned short* xlb = (unsigned short*)(ws + alloc((size_t)NNODES * 512 * 2));
  unsigned short* hA  = (unsigned short*)(ws + alloc((size_t)NNODES * 256 * 2));
  unsigned short* hB  = (unsigned short*)(ws + alloc((size_t)NNODES * 256 * 2));
  float* pool   = (float*)(ws + alloc((size_t)NGRAPH * 768 * 4));
  float* hidden = (float*)(ws + alloc((size_t)NGRAPH * 768 * 4));

  // CSR build
  zero_deg<<<NNODES / 256, 256, 0, stream>>>(deg);
  count_deg<<<NETOT / 256, 256, 0, stream>>>(ei, deg);
  scan1<<<NNODES / 256, 256, 0, stream>>>(deg, incl, bsum);
  scan2<<<1, 64, 0, stream>>>(bsum, boff);
  scan3<<<NNODES / 256, 256, 0, stream>>>(deg, incl, boff, rowoff, cursor);
  fill_csr<<<NETOT / 256, 256, 0, stream>>>(ei, cursor, colsrc);

  dim3 ggrid(NNODES / 128, 4);

  // layer 1 (K=128)
  convX<<<NNODES * 128 / 256, 256, 0, stream>>>(x, xb);
  convW<128><<<128 * 512 / 256, 256, 0, stream>>>(Wl[0], Wr[0], Wt);
  gemm_xw<128><<<ggrid, 256, 0, stream>>>(xb, Wt, xlb);
  edge_agg<<<NNODES / 4, 256, 0, stream>>>(xlb, rowoff, colsrc, att[0], bp[0], hA);
  pool_accum<<<NGRAPH, 256, 0, stream>>>(hA, batch, pool, 0);

  // layer 2 (K=256)
  convW<256><<<256 * 512 / 256, 256, 0, stream>>>(Wl[1], Wr[1], Wt);
  gemm_xw<256><<<ggrid, 256, 0, stream>>>(hA, Wt, xlb);
  edge_agg<<<NNODES / 4, 256, 0, stream>>>(xlb, rowoff, colsrc, att[1], bp[1], hB);
  pool_accum<<<NGRAPH, 256, 0, stream>>>(hB, batch, pool, 1);

  // layer 3 (K=256)
  convW<256><<<256 * 512 / 256, 256, 0, stream>>>(Wl[2], Wr[2], Wt);
  gemm_xw<256><<<ggrid, 256, 0, stream>>>(hB, Wt, xlb);
  edge_agg<<<NNODES / 4, 256, 0, stream>>>(xlb, rowoff, colsrc, att[2], bp[2], hA);
  pool_accum<<<NGRAPH, 256, 0, stream>>>(hA, batch, pool, 2);

  // FFN head
  ffn1<<<dim3(768 / 32, NGRAPH / 32), 256, 0, stream>>>(pool, fW1, fb1, hidden);
  ffn2<<<NGRAPH / 4, 256, 0, stream>>>(hidden, fW2, fb2, (float*)d_out);
}

// Round 7
// 286.337 us; speedup vs baseline: 1.8436x; 1.0133x over previous
//
#include <hip/hip_runtime.h>

#define NNODES 16384
#define NEDGES 524288
#define NETOT  (NEDGES + NNODES)   // 540672 (self-loops appended)
#define NGRAPH 256

typedef __attribute__((ext_vector_type(8))) short short8;
typedef __attribute__((ext_vector_type(4))) float f32x4;
typedef __attribute__((ext_vector_type(2))) float f32x2;

__device__ __forceinline__ float b2f(unsigned short u){
  union { unsigned int i; float f; } v; v.i = ((unsigned int)u) << 16; return v.f;
}
__device__ __forceinline__ unsigned short f2b(float f){
  union { float f; unsigned int i; } v; v.f = f;
  unsigned int r = v.i + 0x7FFFu + ((v.i >> 16) & 1u);
  return (unsigned short)(r >> 16);
}
// unpack 2 bf16 (packed in one u32) -> f32x2
__device__ __forceinline__ f32x2 unpack2(unsigned int u){
  union { unsigned int i; float f; } lo, hi;
  lo.i = u << 16; hi.i = u & 0xFFFF0000u;
  f32x2 r; r[0] = lo.f; r[1] = hi.f; return r;
}

// ---------------- CSR build (dst-sorted) ----------------
__global__ void __launch_bounds__(256) zero_deg(int* __restrict__ deg){
  deg[blockIdx.x * 256 + threadIdx.x] = 0;   // grid = NNODES/256
}

__global__ void __launch_bounds__(256) count_deg(const int* __restrict__ ei, int* __restrict__ deg){
  int i = blockIdx.x * 256 + threadIdx.x;    // grid exactly NETOT/256
  int d = (i < NEDGES) ? ei[NEDGES + i] : (i - NEDGES);
  atomicAdd(&deg[d], 1);
}

// phase 1: per-block (256-elem) inclusive scan + block sums. grid = NNODES/256
__global__ void __launch_bounds__(256) scan1(const int* __restrict__ deg,
                                             int* __restrict__ incl, int* __restrict__ bsum){
  __shared__ int ws[4];
  const int b = blockIdx.x, t = threadIdx.x, lane = t & 63, w = t >> 6;
  int v = deg[b * 256 + t];
  int x = v;
  #pragma unroll
  for(int o = 1; o < 64; o <<= 1){ int u = __shfl_up(x, o, 64); if(lane >= o) x += u; }
  if(lane == 63) ws[w] = x;
  __syncthreads();
  int add = 0;
  #pragma unroll
  for(int j = 0; j < 4; j++) if(j < w) add += ws[j];
  incl[b * 256 + t] = x + add;
  if(t == 255) bsum[b] = x + add;
}

// phase 2(+3): each block reduces bsum[0..b-1] (1 wave) then applies offsets.
__global__ void __launch_bounds__(256) scan3(const int* __restrict__ deg, const int* __restrict__ incl,
                                             const int* __restrict__ bsum,
                                             int* __restrict__ row_off, int* __restrict__ cursor){
  __shared__ int boff_s;
  const int b = blockIdx.x, t = threadIdx.x;
  if(t < 64){
    int v = (t < b) ? bsum[t] : 0;
    #pragma unroll
    for(int o = 32; o > 0; o >>= 1) v += __shfl_xor(v, o, 64);
    if(t == 0) boff_s = v;
  }
  __syncthreads();
  const int i = b * 256 + t;
  int inc = incl[i] + boff_s;
  row_off[i + 1] = inc;
  cursor[i] = inc - deg[i];
  if(i == 0) row_off[0] = 0;
}

__global__ void __launch_bounds__(256) fill_csr(const int* __restrict__ ei, int* __restrict__ cursor,
                                                int* __restrict__ col_src){
  int i = blockIdx.x * 256 + threadIdx.x;  // grid exactly NETOT/256
  int s, d;
  if(i < NEDGES){ s = ei[i]; d = ei[NEDGES + i]; }
  else          { s = i - NEDGES; d = s; }
  int p = atomicAdd(&cursor[d], 1);
  col_src[p] = s;
}

// ---------------- fused prep: convX + convW x3 (all independent of CSR/layers) ----------------
// blocks [0,8192): xb = bf16(x);  then 256 blocks layer1 W, 512 layer2, 512 layer3
__global__ void __launch_bounds__(256) prep(const float* __restrict__ x,
                                            const float* __restrict__ Wl1, const float* __restrict__ Wr1,
                                            const float* __restrict__ Wl2, const float* __restrict__ Wr2,
                                            const float* __restrict__ Wl3, const float* __restrict__ Wr3,
                                            unsigned short* __restrict__ xb,
                                            unsigned short* __restrict__ Wt1,
                                            unsigned short* __restrict__ Wt2,
                                            unsigned short* __restrict__ Wt3){
  const int b = blockIdx.x, t = threadIdx.x;
  if(b < 8192){
    int i = b * 256 + t;
    xb[i] = f2b(x[i]);
    return;
  }
  const float *Wl, *Wr; unsigned short* Wt; int K, i;
  if(b < 8192 + 256){ Wl = Wl1; Wr = Wr1; Wt = Wt1; K = 128; i = (b - 8192) * 256 + t; }
  else if(b < 8192 + 256 + 512){ Wl = Wl2; Wr = Wr2; Wt = Wt2; K = 256; i = (b - 8448) * 256 + t; }
  else { Wl = Wl3; Wr = Wr3; Wt = Wt3; K = 256; i = (b - 8960) * 256 + t; }
  int k = i >> 9, c = i & 511;
  float val = (c < 256) ? Wl[(size_t)k * 256 + c] : Wr[(size_t)k * 256 + (c - 256)];
  Wt[(size_t)c * K + k] = f2b(val);
}

// ---------------- GEMM: xlb[N][512](bf16) = A[N][K](bf16) @ Wt^T ----------------
// tile 128x128, 4 waves, 16 MFMA per wave per 32-k step.
// MFMA 16x16x32_bf16; C/D: col=lane&15, row=(lane>>4)*4+reg
template<int K>
__global__ void __launch_bounds__(256) gemm_xw(const unsigned short* __restrict__ A,
                                               const unsigned short* __restrict__ Wt,
                                               unsigned short* __restrict__ Cout){
  __shared__ unsigned short As[128][40];  // BK=32, padded row stride 80 B
  __shared__ unsigned short Bs[128][40];
  const int t = threadIdx.x;
  const int rowbase = blockIdx.x * 128;
  const int colbase = blockIdx.y * 128;
  const int wave = t >> 6, lane = t & 63;
  const int lrow = lane & 15, kg = lane >> 4;

  f32x4 acc[2][8] = {};

  for(int kt = 0; kt < K; kt += 32){
    { // stage A: 128 rows x 32 k
      int oct = t & 3, r = t >> 2;
      const unsigned short* ga = A + (size_t)(rowbase + r) * K + kt + oct * 8;
      short8 v0 = *(const short8*)ga;
      short8 v1 = *(const short8*)(ga + 64 * K);
      *(short8*)(&As[r][oct * 8])      = v0;
      *(short8*)(&As[r + 64][oct * 8]) = v1;
    }
    { // stage B: Bs[n][k] = Wt[colbase+n][kt+k]
      int n = t & 127, kh = (t >> 7) * 16;
      const unsigned short* gw = Wt + (size_t)(colbase + n) * K + kt + kh;
      short8 v0 = *(const short8*)gw;
      short8 v1 = *(const short8*)(gw + 8);
      *(short8*)(&Bs[n][kh])     = v0;
      *(short8*)(&Bs[n][kh + 8]) = v1;
    }
    __syncthreads();
    short8 afrag[2], bfrag[8];
    afrag[0] = *(const short8*)(&As[wave * 32 + lrow][kg * 8]);
    afrag[1] = *(const short8*)(&As[wave * 32 + 16 + lrow][kg * 8]);
    #pragma unroll
    for(int fc = 0; fc < 8; fc++) bfrag[fc] = *(const short8*)(&Bs[fc * 16 + lrow][kg * 8]);
    #pragma unroll
    for(int rf = 0; rf < 2; rf++)
      #pragma unroll
      for(int fc = 0; fc < 8; fc++)
        acc[rf][fc] = __builtin_amdgcn_mfma_f32_16x16x32_bf16(afrag[rf], bfrag[fc], acc[rf][fc], 0, 0, 0);
    __syncthreads();
  }
  #pragma unroll
  for(int rf = 0; rf < 2; rf++)
    #pragma unroll
    for(int fc = 0; fc < 8; fc++)
      #pragma unroll
      for(int r = 0; r < 4; r++){
        int row = rowbase + wave * 32 + rf * 16 + kg * 4 + r;
        int col = colbase + fc * 16 + lrow;
        Cout[(size_t)row * 512 + col] = f2b(acc[rf][fc][r]);
      }
}

// ---------------- per-dst-node softmax aggregation (4 edges in flight) ----------------
// one wave per dst node. eg = lane>>4 (4 edge groups); lane&15 owns 16 channels
// c0=(lane&15)*16: lanes 0-7 of group = head0, 8-15 = head1. Logit = 8-lane reduce
// (3 shfl). Per lane: 2 independent uint4 gathers -> 4 edges x 2 loads in flight.
// No max-subtraction (|logit| small by construction).
__global__ void __launch_bounds__(256) edge_agg(const unsigned short* __restrict__ xlb,
                                                const int* __restrict__ row_off,
                                                const int* __restrict__ col_src,
                                                const float* __restrict__ att,
                                                const float* __restrict__ bias,
                                                unsigned short* __restrict__ hout){
  const int n = (blockIdx.x * 256 + threadIdx.x) >> 6;
  const int lane = threadIdx.x & 63;
  const int eg = lane >> 4;
  const int c0 = (lane & 15) * 16;
  f32x2 xr[8], at[8];
  {
    const unsigned short* xp = xlb + (size_t)n * 512 + 256 + c0;   // Wr x_dst
    uint4 v0 = *(const uint4*)xp;
    uint4 v1 = *(const uint4*)(xp + 8);
    xr[0] = unpack2(v0.x); xr[1] = unpack2(v0.y); xr[2] = unpack2(v0.z); xr[3] = unpack2(v0.w);
    xr[4] = unpack2(v1.x); xr[5] = unpack2(v1.y); xr[6] = unpack2(v1.z); xr[7] = unpack2(v1.w);
    #pragma unroll
    for(int i = 0; i < 8; i++) at[i] = *(const f32x2*)(att + c0 + 2 * i);
  }
  float s = 0.f;
  f32x2 ac[8] = {};
  const int beg = row_off[n], end = row_off[n + 1];
  for(int ch = beg; ch < end; ch += 64){
    int idx = ch + lane;
    int si = (idx < end) ? col_src[idx] : 0;
    int cnt = end - ch; if(cnt > 64) cnt = 64;
    for(int k = 0; k < cnt; k += 4){
      int kk = k + eg;                       // k<=60, eg<=3 -> kk<=63
      int src = __shfl(si, kk);
      const unsigned short* gp = xlb + (size_t)src * 512 + c0;     // Wl x_src (32B)
      uint4 v0 = *(const uint4*)gp;
      uint4 v1 = *(const uint4*)(gp + 8);
      f32x2 x0 = unpack2(v0.x), x1 = unpack2(v0.y), x2 = unpack2(v0.z), x3 = unpack2(v0.w);
      f32x2 x4 = unpack2(v1.x), x5 = unpack2(v1.y), x6 = unpack2(v1.z), x7 = unpack2(v1.w);
      f32x2 e, p2;
      e = x0 + xr[0]; e = __builtin_elementwise_max(e, e * 0.2f); p2  = e * at[0];
      e = x1 + xr[1]; e = __builtin_elementwise_max(e, e * 0.2f); p2 += e * at[1];
      e = x2 + xr[2]; e = __builtin_elementwise_max(e, e * 0.2f); p2 += e * at[2];
      e = x3 + xr[3]; e = __builtin_elementwise_max(e, e * 0.2f); p2 += e * at[3];
      e = x4 + xr[4]; e = __builtin_elementwise_max(e, e * 0.2f); p2 += e * at[4];
      e = x5 + xr[5]; e = __builtin_elementwise_max(e, e * 0.2f); p2 += e * at[5];
      e = x6 + xr[6]; e = __builtin_elementwise_max(e, e * 0.2f); p2 += e * at[6];
      e = x7 + xr[7]; e = __builtin_elementwise_max(e, e * 0.2f); p2 += e * at[7];
      float p = p2[0] + p2[1];
      p += __shfl_xor(p, 1); p += __shfl_xor(p, 2); p += __shfl_xor(p, 4);  // 8-lane head reduce
      float pe = (kk < cnt) ? __expf(p) : 0.f;
      s += pe;
      f32x2 pe2 = {pe, pe};
      ac[0] += pe2 * x0; ac[1] += pe2 * x1; ac[2] += pe2 * x2; ac[3] += pe2 * x3;
      ac[4] += pe2 * x4; ac[5] += pe2 * x5; ac[6] += pe2 * x6; ac[7] += pe2 * x7;
    }
  }
  // combine the 4 edge groups (same channel slice lives at lane&15)
  s += __shfl_xor(s, 16); s += __shfl_xor(s, 32);
  #pragma unroll
  for(int i = 0; i < 8; i++){
    ac[i][0] += __shfl_xor(ac[i][0], 16); ac[i][0] += __shfl_xor(ac[i][0], 32);
    ac[i][1] += __shfl_xor(ac[i][1], 16); ac[i][1] += __shfl_xor(ac[i][1], 32);
  }
  if(eg == 0){
    float inv = 1.f / s;
    unsigned short o[16];
    #pragma unroll
    for(int i = 0; i < 8; i++){
      o[2 * i]     = f2b(fmaf(ac[i][0], inv, bias[c0 + 2 * i]));
      o[2 * i + 1] = f2b(fmaf(ac[i][1], inv, bias[c0 + 2 * i + 1]));
    }
    unsigned short* hp = hout + (size_t)n * 256 + c0;
    *(uint4*)hp       = *(const uint4*)&o[0];
    *(uint4*)(hp + 8) = *(const uint4*)&o[8];
  }
}

// ---------------- pooling (node-parallel x8) ----------------
__device__ __forceinline__ int lbound(const int* __restrict__ a, int n, int v){
  int lo = 0, hi = n;
  while(lo < hi){ int mid = (lo + hi) >> 1; if(a[mid] < v) lo = mid + 1; else hi = mid; }
  return lo;
}

__global__ void __launch_bounds__(256) pool_accum(const unsigned short* __restrict__ h,
                                                  const int* __restrict__ batch,
                                                  float* __restrict__ pool, int slot){
  __shared__ float red[8][264];
  const int g = blockIdx.x, t = threadIdx.x;
  const int ng = t >> 5, c0 = (t & 31) * 8;
  const int lo = lbound(batch, NNODES, g);
  const int hi = lbound(batch, NNODES, g + 1);
  f32x2 a0 = {0.f,0.f}, a1 = {0.f,0.f}, a2 = {0.f,0.f}, a3 = {0.f,0.f};
  for(int node = lo + ng; node < hi; node += 8){
    uint4 v = *(const uint4*)(h + (size_t)node * 256 + c0);
    a0 += unpack2(v.x); a1 += unpack2(v.y); a2 += unpack2(v.z); a3 += unpack2(v.w);
  }
  red[ng][c0 + 0] = a0[0]; red[ng][c0 + 1] = a0[1];
  red[ng][c0 + 2] = a1[0]; red[ng][c0 + 3] = a1[1];
  red[ng][c0 + 4] = a2[0]; red[ng][c0 + 5] = a2[1];
  red[ng][c0 + 6] = a3[0]; red[ng][c0 + 7] = a3[1];
  __syncthreads();
  float s = 0.f;
  #pragma unroll
  for(int i = 0; i < 8; i++) s += red[i][t];
  pool[(size_t)g * 768 + slot * 256 + t] = s;
}

// ---------------- FFN ----------------
__global__ void __launch_bounds__(256) ffn1(const float* __restrict__ pool,
                                            const float* __restrict__ fW1,
                                            const float* __restrict__ fb1,
                                            float* __restrict__ hidden){
  __shared__ float ap[32][65];   // [graph][k]
  __shared__ float ws[64][33];   // [k][col]
  const int t = threadIdx.x;
  const int cb = blockIdx.x * 32;
  const int gb = blockIdx.y * 32;
  const int tc = t & 31, tg = t >> 5;
  float acc[4] = {};
  for(int kc = 0; kc < 768; kc += 64){
    {
      int g_l = t >> 3, j8 = (t & 7) * 8;
      const float* gp = pool + (size_t)(gb + g_l) * 768 + kc + j8;
      #pragma unroll
      for(int i = 0; i < 8; i++) ap[g_l][j8 + i] = gp[i];
    }
    {
      int c_l = t & 31, k0 = (t >> 5) * 8;
      #pragma unroll
      for(int i = 0; i < 8; i++) ws[k0 + i][c_l] = fW1[(size_t)(kc + k0 + i) * 768 + cb + c_l];
    }
    __syncthreads();
    #pragma unroll
    for(int k = 0; k < 64; k++){
      float w = ws[k][tc];
      #pragma unroll
      for(int i = 0; i < 4; i++) acc[i] = fmaf(ap[tg * 4 + i][k], w, acc[i]);
    }
    __syncthreads();
  }
  float b = fb1[cb + tc];
  #pragma unroll
  for(int i = 0; i < 4; i++)
    hidden[(size_t)(gb + tg * 4 + i) * 768 + cb + tc] = fmaxf(acc[i] + b, 0.f);
}

__global__ void __launch_bounds__(256) ffn2(const float* __restrict__ hidden,
                                            const float* __restrict__ fW2,
                                            const float* __restrict__ fb2,
                                            float* __restrict__ out){
  const int g = (blockIdx.x * 256 + threadIdx.x) >> 6;   // one wave per graph
  const int lane = threadIdx.x & 63;
  float p = 0.f;
  for(int i = lane; i < 768; i += 64) p += hidden[(size_t)g * 768 + i] * fW2[i];
  #pragma unroll
  for(int o = 32; o > 0; o >>= 1) p += __shfl_xor(p, o, 64);
  if(lane == 0) out[g] = p + fb2[0];
}

extern "C" void kernel_launch(void* const* d_in, const int* in_sizes, int n_in,
                              void* d_out, int out_size, void* d_ws, size_t ws_size,
                              hipStream_t stream){
  const float* x    = (const float*)d_in[0];
  const int* ei     = (const int*)d_in[1];
  const int* batch  = (const int*)d_in[2];
  const float* Wl[3]  = {(const float*)d_in[3],  (const float*)d_in[7],  (const float*)d_in[11]};
  const float* Wr[3]  = {(const float*)d_in[4],  (const float*)d_in[8],  (const float*)d_in[12]};
  const float* att[3] = {(const float*)d_in[5],  (const float*)d_in[9],  (const float*)d_in[13]};
  const float* bp[3]  = {(const float*)d_in[6],  (const float*)d_in[10], (const float*)d_in[14]};
  const float* fW1 = (const float*)d_in[15];
  const float* fb1 = (const float*)d_in[16];
  const float* fW2 = (const float*)d_in[17];
  const float* fb2 = (const float*)d_in[18];

  char* ws = (char*)d_ws;
  size_t off = 0;
  auto alloc = [&](size_t sz){ size_t p = off; off += (sz + 255) & ~(size_t)255; return p; };
  int* deg      = (int*)(ws + alloc((size_t)NNODES * 4));
  int* rowoff   = (int*)(ws + alloc((size_t)(NNODES + 1) * 4));
  int* cursor   = (int*)(ws + alloc((size_t)NNODES * 4));
  int* colsrc   = (int*)(ws + alloc((size_t)NETOT * 4));
  int* incl     = (int*)(ws + alloc((size_t)NNODES * 4));
  int* bsum     = (int*)(ws + alloc(64 * 4));
  unsigned short* xb  = (unsigned short*)(ws + alloc((size_t)NNODES * 128 * 2));
  unsigned short* Wt1 = (unsigned short*)(ws + alloc((size_t)512 * 128 * 2));
  unsigned short* Wt2 = (unsigned short*)(ws + alloc((size_t)512 * 256 * 2));
  unsigned short* Wt3 = (unsigned short*)(ws + alloc((size_t)512 * 256 * 2));
  unsigned short* xlb = (unsigned short*)(ws + alloc((size_t)NNODES * 512 * 2));
  unsigned short* hA  = (unsigned short*)(ws + alloc((size_t)NNODES * 256 * 2));
  unsigned short* hB  = (unsigned short*)(ws + alloc((size_t)NNODES * 256 * 2));
  float* pool   = (float*)(ws + alloc((size_t)NGRAPH * 768 * 4));
  float* hidden = (float*)(ws + alloc((size_t)NGRAPH * 768 * 4));

  // CSR build + all input conversions (prep is independent, overlaps CSR chain)
  zero_deg<<<NNODES / 256, 256, 0, stream>>>(deg);
  count_deg<<<NETOT / 256, 256, 0, stream>>>(ei, deg);
  prep<<<8192 + 256 + 512 + 512, 256, 0, stream>>>(x, Wl[0], Wr[0], Wl[1], Wr[1], Wl[2], Wr[2],
                                                   xb, Wt1, Wt2, Wt3);
  scan1<<<NNODES / 256, 256, 0, stream>>>(deg, incl, bsum);
  scan3<<<NNODES / 256, 256, 0, stream>>>(deg, incl, bsum, rowoff, cursor);
  fill_csr<<<NETOT / 256, 256, 0, stream>>>(ei, cursor, colsrc);

  dim3 ggrid(NNODES / 128, 4);

  // layer 1 (K=128)
  gemm_xw<128><<<ggrid, 256, 0, stream>>>(xb, Wt1, xlb);
  edge_agg<<<NNODES / 4, 256, 0, stream>>>(xlb, rowoff, colsrc, att[0], bp[0], hA);
  pool_accum<<<NGRAPH, 256, 0, stream>>>(hA, batch, pool, 0);

  // layer 2 (K=256)
  gemm_xw<256><<<ggrid, 256, 0, stream>>>(hA, Wt2, xlb);
  edge_agg<<<NNODES / 4, 256, 0, stream>>>(xlb, rowoff, colsrc, att[1], bp[1], hB);
  pool_accum<<<NGRAPH, 256, 0, stream>>>(hB, batch, pool, 1);

  // layer 3 (K=256)
  gemm_xw<256><<<ggrid, 256, 0, stream>>>(hB, Wt3, xlb);
  edge_agg<<<NNODES / 4, 256, 0, stream>>>(xlb, rowoff, colsrc, att[2], bp[2], hA);
  pool_accum<<<NGRAPH, 256, 0, stream>>>(hA, batch, pool, 2);

  // FFN head
  ffn1<<<dim3(768 / 32, NGRAPH / 32), 256, 0, stream>>>(pool, fW1, fb1, hidden);
  ffn2<<<NGRAPH / 4, 256, 0, stream>>>(hidden, fW2, fb2, (float*)d_out);
}